// Round 5
// baseline (1211.423 us; speedup 1.0000x reference)
//
#include <hip/hip_runtime.h>
#include <math.h>

#define BB 8
#define TT 16
#define SS 400
#define HH 512
#define EE 128
#define VV 50000
#define VE 50050
#define OOVn 50

// output offsets (floats)
#define O1 6406400
#define O2 6410496
#define O3 6414592
#define O4 6418688
#define O5 6469888
#define O6 6469896

// scratch inside out0 logits region (float offsets; dead until gemm_logits)
#define G_OFF    0          // 2048x1152 ushort = 1,179,648 f
#define EWHB_OFF 1179648    // 512x512  ushort =   131,072 f -> ends 1,310,720
#define ENCG_OFF 1310720    // 8x2048x400 ushort = 3,276,800 f -> ends 4,587,520
#define ENCP_OFF 4600000    // 3200x512 ushort = 819,200 f -> ends 5,419,200
#define PM_OFF   5700000    // 16x8x400 fp32 = 51,200 f -> ends 5,751,200

typedef __attribute__((ext_vector_type(4))) float floatx4;
typedef __attribute__((ext_vector_type(8))) short short8;
typedef __attribute__((ext_vector_type(8))) unsigned short ushort8_t;
typedef __attribute__((ext_vector_type(4))) unsigned short ushort4_t;

__device__ __forceinline__ float sigm(float x){ return 1.0f/(1.0f+__expf(-x)); }
__device__ __forceinline__ float ftanh(float x){
  float e = __expf(2.0f*x); return 1.0f - 2.0f/(e + 1.0f);
}
__device__ __forceinline__ unsigned short f2bf(float f){
  union { float f; unsigned int u; } v; v.f = f;
  unsigned int u = v.u;
  return (unsigned short)((u + 0x7FFFu + ((u >> 16) & 1u)) >> 16);
}
__device__ __forceinline__ float bfu(unsigned short u){
  union { unsigned int i; float f; } v; v.i = ((unsigned int)u) << 16; return v.f;
}
__device__ __forceinline__ short8 cvt8(float4 a, float4 b){
  short8 r;
  r[0]=(short)f2bf(a.x); r[1]=(short)f2bf(a.y); r[2]=(short)f2bf(a.z); r[3]=(short)f2bf(a.w);
  r[4]=(short)f2bf(b.x); r[5]=(short)f2bf(b.y); r[6]=(short)f2bf(b.z); r[7]=(short)f2bf(b.w);
  return r;
}

// ---------------------------------------------------------------------------
// LDS-free GEMM: C[M,N] = A[M,K] @ B[N,K]^T (+bias). MFMA fragments loaded
// directly from global (16 B/lane), fp32->bf16 converted in registers.
// No barriers in the K-loop -> loads across iterations stay in flight.
// Tile 128(M) x 64(N); M multiple of 128; N ragged-guarded; K multiple of 32.
// ABF: A is bf16 (ushort) with leading dim lda; else fp32.
// OBF: store bf16. EXPO: store exp(val) fp32 + per-row sum into rowsum[128].
// PERM: C row = (m&7)*16 + (m>>3) (m = t*8+b -> b*16+t), M must be 128.
// ---------------------------------------------------------------------------
template<int ABF, int OBF, int EXPO, int PERM>
__global__ __launch_bounds__(256) void gemm_direct(
    const void* __restrict__ Ap, int lda,
    const float* __restrict__ Bm, int ldb,
    const float* __restrict__ bias,
    void* __restrict__ Cp, long ldc,
    int N, int K, long bsB, long bsC,
    float* __restrict__ rowsum)
{
  __shared__ float rowpart[128];
  int tid = threadIdx.x;
  int mbase = blockIdx.x * 128;
  int nbase = blockIdx.y * 64;
  const float* Bz = Bm + (long)blockIdx.z * bsB;
  int wave = tid >> 6, lane = tid & 63;
  int wm = (wave & 1)*64, wn = (wave >> 1)*32;
  int fl = lane & 15, quad = lane >> 4;
  int koff = quad * 8;

  floatx4 acc[4][2];
#pragma unroll
  for (int i=0;i<4;i++) for(int j=0;j<2;j++) acc[i][j] = (floatx4)(0.0f);
  if (EXPO && tid < 128) rowpart[tid] = 0.f;

  int arow[4];
#pragma unroll
  for (int i=0;i<4;i++) arow[i] = mbase + wm + i*16 + fl;
  int brow[2]; bool bok[2];
#pragma unroll
  for (int j=0;j<2;j++){ int gn = nbase + wn + j*16 + fl; bok[j] = gn < N; brow[j] = bok[j] ? gn : 0; }

#pragma unroll 2
  for (int kc = 0; kc < K; kc += 32) {
    short8 af[4], bfr[2];
    if (ABF) {
      const unsigned short* Au = (const unsigned short*)Ap;
#pragma unroll
      for (int i=0;i<4;i++)
        af[i] = *(const short8*)(Au + (size_t)arow[i]*lda + kc + koff);
    } else {
      const float* Af = (const float*)Ap;
#pragma unroll
      for (int i=0;i<4;i++) {
        const float* p = Af + (size_t)arow[i]*lda + kc + koff;
        float4 a0 = *(const float4*)p;
        float4 a1 = *(const float4*)(p+4);
        af[i] = cvt8(a0, a1);
      }
    }
#pragma unroll
    for (int j=0;j<2;j++) {
      if (bok[j]) {
        const float* p = Bz + (size_t)brow[j]*ldb + kc + koff;
        float4 b0 = *(const float4*)p;
        float4 b1 = *(const float4*)(p+4);
        bfr[j] = cvt8(b0, b1);
      } else {
        bfr[j] = (short8)(short)0;
      }
    }
#pragma unroll
    for (int i=0;i<4;i++)
#pragma unroll
      for (int j=0;j<2;j++)
        acc[i][j] = __builtin_amdgcn_mfma_f32_16x16x32_bf16(af[i], bfr[j], acc[i][j], 0,0,0);
  }

  if (EXPO) __syncthreads();
#pragma unroll
  for (int i=0;i<4;i++){
#pragma unroll
    for (int r=0;r<4;r++){
      int mg = mbase + wm + i*16 + quad*4 + r;
      int orow = PERM ? ((mg & 7)*16 + (mg >> 3)) : mg;
      float rs = 0.f;
#pragma unroll
      for (int j=0;j<2;j++){
        int nc = nbase + wn + j*16 + fl;
        if (nc >= N) continue;
        float v = acc[i][j][r] + (bias ? bias[nc] : 0.f);
        long ci = (long)orow*ldc + nc + (long)blockIdx.z*bsC;
        if (EXPO) {
          float e = __expf(v);
          ((float*)Cp)[ci] = e;
          rs += e;
        } else if (OBF) {
          ((unsigned short*)Cp)[ci] = f2bf(v);
        } else {
          ((float*)Cp)[ci] = v;
        }
      }
      if (EXPO) atomicAdd(&rowpart[mg & 127], rs);
    }
  }
  if (EXPO) {
    __syncthreads();
    if (tid < 128) {
      int orow = (tid & 7)*16 + (tid >> 3);
      atomicAdd(&rowsum[orow], rowpart[tid]);
    }
  }
}

// ---------------------------------------------------------------------------
// Prologue P1: G = [Wx = W_ih@xctx_w (640) | W_hh (512)] bf16 (2048x1152);
// plus ewhb = bf16(energy_w[:, :512]).  grid 1280.
// ---------------------------------------------------------------------------
__global__ __launch_bounds__(256) void p_wx(const float* __restrict__ wih,
    const float* __restrict__ whh, const float* __restrict__ xcw,
    const float* __restrict__ ew,
    unsigned short* __restrict__ G, unsigned short* __restrict__ ewhb)
{
  int blk = blockIdx.x, tid = threadIdx.x;
  if (blk < 640) {
    int rt = blk / 10, ct = blk % 10;
    __shared__ float wl[32*128];
    __shared__ float xl[128*64];
    for (int i = tid; i < 4096; i += 256) {
      int r = i >> 7, k = i & 127;
      wl[i] = wih[(size_t)(rt*32+r)*128 + k];
    }
    for (int i = tid; i < 8192; i += 256) {
      int e = i >> 6, c = i & 63;
      xl[i] = xcw[(size_t)e*640 + ct*64 + c];
    }
    __syncthreads();
    for (int o = tid; o < 2048; o += 256) {
      int r = o >> 6, c = o & 63;
      float acc = 0.f;
      for (int e = 0; e < 128; ++e) acc += wl[r*128+e]*xl[e*64+c];
      G[(size_t)(rt*32+r)*1152 + ct*64 + c] = f2bf(acc);
    }
  } else if (blk < 1152) {
    int idx = blk - 640;  // 0..511
    for (int q = 0; q < 2; ++q) {
      int n = idx*2048 + q*1024 + tid*4;
      int r = n >> 9, k = n & 511;
      float4 v = *(const float4*)(whh + n);
      ushort4_t s; s[0]=f2bf(v.x); s[1]=f2bf(v.y); s[2]=f2bf(v.z); s[3]=f2bf(v.w);
      *(ushort4_t*)(G + (size_t)r*1152 + 640 + k) = s;
    }
  } else {
    int idx = blk - 1152;  // 0..127
    for (int q = 0; q < 2; ++q) {
      size_t n = (size_t)idx*2048 + q*1024 + tid*4;
      int p = (int)(n >> 9), k = (int)(n & 511);
      float4 v = *(const float4*)(ew + (size_t)p*1024 + k);
      ushort4_t s; s[0]=f2bf(v.x); s[1]=f2bf(v.y); s[2]=f2bf(v.z); s[3]=f2bf(v.w);
      *(ushort4_t*)(ewhb + n) = s;
    }
  }
}

// Prologue P2: gb = b_ih+b_hh+W_ih@xb ; q = xctx_w^T@pw_x ; qb ; zero d1/d2
__global__ __launch_bounds__(256) void p_small(const float* __restrict__ wih,
    const float* __restrict__ bih, const float* __restrict__ bhh,
    const float* __restrict__ xb, const float* __restrict__ xcw,
    const float* __restrict__ pw, const float* __restrict__ pb,
    float* __restrict__ gb, float* __restrict__ q, float* __restrict__ qb,
    float* __restrict__ d1, float* __restrict__ d2)
{
  int blk = blockIdx.x, tid = threadIdx.x;
  if (blk < 8) {
    __shared__ float xbl[128];
    if (tid < 128) xbl[tid] = xb[tid];
    __syncthreads();
    int r = blk*256 + tid;
    const float* wr = wih + (size_t)r*128;
    float acc = bih[r] + bhh[r];
    for (int e = 0; e < 128; ++e) acc += wr[e]*xbl[e];
    gb[r] = acc;
  } else if (blk < 11) {
    int o = (blk-8)*256 + tid;
    if (o < 640) {
      float acc = 0.f;
      for (int e = 0; e < 128; ++e) acc += pw[1024+e]*xcw[(size_t)e*640 + o];
      q[o] = acc;
    }
  } else {
    if (tid == 0) {
      float acc = 0.f;
      for (int e = 0; e < 128; ++e) acc += pw[1024+e]*xb[e];
      qb[0] = acc + pb[0];
    }
    if (tid < 128) { d1[tid] = 0.f; d2[tid] = 0.f; }
  }
}

// ---------------------------------------------------------------------------
// S1: gates[r,b] = gb + G_emb@emb + G_h@h(t-1) + ctx-part -> LSTM -> h(t),c(t)
//   ctx-part: t==0: G_ctx @ context;  t>=1: sum_s probs(t-1)[s] * encG[b,r,s]
// Also (blk<8, t>=1): writes out4/out6 for step t-1.
// ---------------------------------------------------------------------------
__global__ __launch_bounds__(256) void s1g(
    const unsigned short* __restrict__ G, const unsigned short* __restrict__ encG,
    const float* __restrict__ gb,
    const float* __restrict__ emb, const float* __restrict__ context,
    const float* __restrict__ h0, const float* __restrict__ c0,
    const float* __restrict__ coverage,
    const float* __restrict__ PM, const float* __restrict__ d1,
    const float* __restrict__ d2,
    float* __restrict__ A1, float* __restrict__ c_cur,
    float* __restrict__ out, int t)
{
  __shared__ float ueh[8][644];   // [emb(128) | h(512)]
  __shared__ float uc[8][516];    // t==0: context(512) ; t>=1: probs(400)
  __shared__ float part[256];
  __shared__ float gl[64];
  __shared__ float invs[8];
  int tid = threadIdx.x, blk = blockIdx.x;

  if (t >= 1 && tid < 8)
    invs[tid] = 1.0f / (d2[(t-1)*8 + tid] + 1e-12f*d1[(t-1)*8 + tid]);
  __syncthreads();

  for (int i = 0; i < 5; ++i) {
    int slot = i*256 + tid;
    int b = slot / 160, sl = slot - b*160;
    if (sl < 32) {
      *(float4*)&ueh[b][sl*4] = *(const float4*)(emb + (size_t)(b*16+t)*128 + sl*4);
    } else {
      int qq = sl - 32;
      const float* hsrc = t ? (A1 + ((size_t)((t-1)*8+b))*1024) : (h0 + b*512);
      *(float4*)&ueh[b][128 + qq*4] = *(const float4*)(hsrc + qq*4);
    }
  }
  if (t == 0) {
    for (int i = 0; i < 4; ++i) {
      int slot = i*256 + tid;
      int b = slot >> 7, sl = slot & 127;
      *(float4*)&uc[b][sl*4] = *(const float4*)(context + b*512 + sl*4);
    }
  } else {
    const float* pmsrc = PM + (size_t)(t-1)*3200;
    for (int i = 0; i < 4; ++i) {
      int slot = i*256 + tid;
      if (slot < 800) {
        int b = slot / 100, sl = slot - b*100;
        float4 p4 = *(const float4*)(pmsrc + b*400 + sl*4);
        float iv = invs[b];
        p4.x *= iv; p4.y *= iv; p4.z *= iv; p4.w *= iv;
        *(float4*)&uc[b][sl*4] = p4;
      }
    }
  }
  __syncthreads();

  if (t >= 1 && blk < 8) {
    int b = blk;
    const float* covprev = (t == 1) ? (coverage + b*400)
                                    : (out + O6 + ((size_t)(b*16 + t-2))*400);
    size_t o = ((size_t)(b*16 + t-1))*400;
    for (int s = tid; s < 400; s += 256) {
      float pr = uc[b][s];
      out[O4 + o + s] = pr;
      out[O6 + o + s] = covprev[s] + pr;
    }
  }

  int dot = tid >> 2, kq = tid & 3;
  int rr = dot >> 3, b = dot & 7;
  int gate = rr >> 1, jj = rr & 1;
  int r = gate*512 + blk*2 + jj;
  const unsigned short* gr = G + (size_t)r*1152;
  float acc = 0.f;
  {
    const unsigned short* gp = gr + kq*8;
    const float* up = &ueh[b][kq*8];
#pragma unroll
    for (int i = 0; i < 4; ++i) {
      ushort8_t w8 = *(const ushort8_t*)(gp + i*32);
      float4 u0 = *(const float4*)(up + i*32);
      float4 u1 = *(const float4*)(up + i*32 + 4);
      acc += bfu(w8[0])*u0.x + bfu(w8[1])*u0.y + bfu(w8[2])*u0.z + bfu(w8[3])*u0.w
           + bfu(w8[4])*u1.x + bfu(w8[5])*u1.y + bfu(w8[6])*u1.z + bfu(w8[7])*u1.w;
    }
  }
  {
    const unsigned short* gp = gr + 640 + kq*8;
    const float* up = &ueh[b][128 + kq*8];
#pragma unroll 4
    for (int i = 0; i < 16; ++i) {
      ushort8_t w8 = *(const ushort8_t*)(gp + i*32);
      float4 u0 = *(const float4*)(up + i*32);
      float4 u1 = *(const float4*)(up + i*32 + 4);
      acc += bfu(w8[0])*u0.x + bfu(w8[1])*u0.y + bfu(w8[2])*u0.z + bfu(w8[3])*u0.w
           + bfu(w8[4])*u1.x + bfu(w8[5])*u1.y + bfu(w8[6])*u1.z + bfu(w8[7])*u1.w;
    }
  }
  if (t == 0) {
    const unsigned short* gp = gr + 128 + kq*8;
    const float* up = &uc[b][kq*8];
#pragma unroll 4
    for (int i = 0; i < 16; ++i) {
      ushort8_t w8 = *(const ushort8_t*)(gp + i*32);
      float4 u0 = *(const float4*)(up + i*32);
      float4 u1 = *(const float4*)(up + i*32 + 4);
      acc += bfu(w8[0])*u0.x + bfu(w8[1])*u0.y + bfu(w8[2])*u0.z + bfu(w8[3])*u0.w
           + bfu(w8[4])*u1.x + bfu(w8[5])*u1.y + bfu(w8[6])*u1.z + bfu(w8[7])*u1.w;
    }
  } else {
    const unsigned short* gp = encG + ((size_t)(b*2048 + r))*400 + kq*8;
    const float* up = &uc[b][kq*8];
#pragma unroll 4
    for (int i = 0; i < 12; ++i) {
      ushort8_t w8 = *(const ushort8_t*)(gp + i*32);
      float4 u0 = *(const float4*)(up + i*32);
      float4 u1 = *(const float4*)(up + i*32 + 4);
      acc += bfu(w8[0])*u0.x + bfu(w8[1])*u0.y + bfu(w8[2])*u0.z + bfu(w8[3])*u0.w
           + bfu(w8[4])*u1.x + bfu(w8[5])*u1.y + bfu(w8[6])*u1.z + bfu(w8[7])*u1.w;
    }
    if (kq < 2) {
      ushort8_t w8 = *(const ushort8_t*)(gp + 12*32);
      float4 u0 = *(const float4*)(up + 12*32);
      float4 u1 = *(const float4*)(up + 12*32 + 4);
      acc += bfu(w8[0])*u0.x + bfu(w8[1])*u0.y + bfu(w8[2])*u0.z + bfu(w8[3])*u0.w
           + bfu(w8[4])*u1.x + bfu(w8[5])*u1.y + bfu(w8[6])*u1.z + bfu(w8[7])*u1.w;
    }
  }
  part[tid] = acc;
  __syncthreads();
  if (tid < 64) {
    int rr2 = tid >> 3;
    int r2 = (rr2 >> 1)*512 + blk*2 + (rr2 & 1);
    gl[tid] = part[tid*4] + part[tid*4+1] + part[tid*4+2] + part[tid*4+3] + gb[r2];
  }
  __syncthreads();
  if (tid < 16) {
    int jj2 = tid >> 3, b2 = tid & 7;
    float gi = gl[(0*2+jj2)*8 + b2];
    float gf = gl[(1*2+jj2)*8 + b2];
    float gg = gl[(2*2+jj2)*8 + b2];
    float go = gl[(3*2+jj2)*8 + b2];
    int j = blk*2 + jj2;
    float cp = t ? c_cur[b2*512+j] : c0[b2*512+j];
    float cn = sigm(gf)*cp + sigm(gi)*ftanh(gg);
    float hn = sigm(go)*ftanh(cn);
    c_cur[b2*512+j] = cn;
    A1[((size_t)(t*8+b2))*1024 + j] = hn;
  }
}

// ---------------------------------------------------------------------------
// S23: fused hp + energy + exp. 64 blocks (8 b x 8 s-chunks of 50).
// Each block redundantly computes hp[b,:] (ewhb is L2-resident), then its
// 50-s slice of pm = exp(e)*mask with atomic D1/D2 accumulation.
// ---------------------------------------------------------------------------
__global__ __launch_bounds__(256) void s23(
    const unsigned short* __restrict__ ewhb, const float* __restrict__ eb,
    const float* __restrict__ A1, const unsigned short* __restrict__ encpb,
    const float* __restrict__ vvec, const float* __restrict__ covw,
    const float* __restrict__ masks, const float* __restrict__ coverage,
    const float* __restrict__ out6v, float* __restrict__ PM,
    float* __restrict__ d1, float* __restrict__ d2, int t)
{
  int tid = threadIdx.x;
  int b = blockIdx.x >> 3, sc = blockIdx.x & 7;
  __shared__ float hl[512];
  __shared__ float hps[512];
  __shared__ float red1[4], red2[4];
  for (int k = tid; k < 512; k += 256) hl[k] = A1[((size_t)(t*8+b))*1024 + k];
  __syncthreads();
#pragma unroll
  for (int pi = 0; pi < 2; ++pi) {
    int p = tid + pi*256;
    const unsigned short* wp = ewhb + (size_t)p*512;
    float acc = 0.f;
#pragma unroll 4
    for (int k = 0; k < 512; k += 8) {
      ushort8_t w8 = *(const ushort8_t*)(wp + k);
      float4 u0 = *(const float4*)(hl + k);
      float4 u1 = *(const float4*)(hl + k + 4);
      acc += bfu(w8[0])*u0.x + bfu(w8[1])*u0.y + bfu(w8[2])*u0.z + bfu(w8[3])*u0.w
           + bfu(w8[4])*u1.x + bfu(w8[5])*u1.y + bfu(w8[6])*u1.z + bfu(w8[7])*u1.w;
    }
    hps[p] = eb[p] + acc;
  }
  __syncthreads();
  int w = tid >> 6, lane = tid & 63;
  int h0i = lane*8;
  float hpv[8], vv[8], cw[8];
  {
    float4 a0 = *(const float4*)&hps[h0i], a1 = *(const float4*)&hps[h0i+4];
    hpv[0]=a0.x; hpv[1]=a0.y; hpv[2]=a0.z; hpv[3]=a0.w;
    hpv[4]=a1.x; hpv[5]=a1.y; hpv[6]=a1.z; hpv[7]=a1.w;
    float4 v0 = *(const float4*)(vvec+h0i), v1 = *(const float4*)(vvec+h0i+4);
    vv[0]=v0.x; vv[1]=v0.y; vv[2]=v0.z; vv[3]=v0.w;
    vv[4]=v1.x; vv[5]=v1.y; vv[6]=v1.z; vv[7]=v1.w;
    float4 c0v = *(const float4*)(covw+h0i), c1v = *(const float4*)(covw+h0i+4);
    cw[0]=c0v.x; cw[1]=c0v.y; cw[2]=c0v.z; cw[3]=c0v.w;
    cw[4]=c1v.x; cw[5]=c1v.y; cw[6]=c1v.z; cw[7]=c1v.w;
  }
  const float* covp = t ? (out6v + ((size_t)(b*16 + t-1))*400) : (coverage + b*400);
  float a1s = 0.f, a2s = 0.f;
  for (int sl = w; sl < 50; sl += 4) {
    int s = sc*50 + sl;
    float cv = covp[s];
    const unsigned short* ep = encpb + ((size_t)(b*400+s))*512 + h0i;
    ushort8_t e8 = *(const ushort8_t*)ep;
    float acc = 0.f;
#pragma unroll
    for (int i = 0; i < 8; ++i)
      acc += ftanh(hpv[i] + bfu(e8[i]) + cv*cw[i]) * vv[i];
    for (int off = 32; off > 0; off >>= 1) acc += __shfl_down(acc, off);
    if (lane == 0) {
      float pe = __expf(acc);
      float pmv = pe * masks[b*400 + s];
      PM[(size_t)t*3200 + b*400 + s] = pmv;
      a1s += pe; a2s += pmv;
    }
  }
  if (lane == 0) { red1[w] = a1s; red2[w] = a2s; }
  __syncthreads();
  if (tid == 0) {
    atomicAdd(&d1[t*8+b], red1[0]+red1[1]+red1[2]+red1[3]);
    atomicAdd(&d2[t*8+b], red2[0]+red2[1]+red2[2]+red2[3]);
  }
}

// ctx for ALL t (post-loop): A1 ctx cols; also out4/out6 for t=15.
__global__ __launch_bounds__(256) void ctx_all(
    const float* __restrict__ PM, const float* __restrict__ d1,
    const float* __restrict__ d2, const float* __restrict__ enc,
    float* __restrict__ A1, float* __restrict__ out)
{
  int tid = threadIdx.x;
  int b = blockIdx.x >> 2, cc = blockIdx.x & 3;
  __shared__ float prl[16][400];
  __shared__ float redbuf[16][128];
  __shared__ float invs[16];
  if (tid < 16) invs[tid] = 1.0f / (d2[tid*8+b] + 1e-12f*d1[tid*8+b]);
  __syncthreads();
  for (int i = 0; i < 7; ++i) {
    int slot = i*256 + tid;
    if (slot < 1600) {
      int tt = slot / 100, sl = slot - tt*100;
      float4 p4 = *(const float4*)(PM + (size_t)tt*3200 + b*400 + sl*4);
      float iv = invs[tt];
      p4.x *= iv; p4.y *= iv; p4.z *= iv; p4.w *= iv;
      *(float4*)&prl[tt][sl*4] = p4;
    }
  }
  __syncthreads();
  if (cc == 0) {
    size_t o15 = ((size_t)(b*16 + 15))*400;
    size_t o14 = ((size_t)(b*16 + 14))*400;
    for (int s = tid; s < 400; s += 256) {
      float pr = prl[15][s];
      out[O4 + o15 + s] = pr;
      out[O6 + o15 + s] = out[O6 + o14 + s] + pr;
    }
  }
  int c = cc*128 + (tid & 127);
  int sg = tid >> 7;
  float acc[16];
#pragma unroll
  for (int tt = 0; tt < 16; ++tt) acc[tt] = 0.f;
  for (int s = sg*200; s < sg*200 + 200; ++s) {
    float ev = enc[((size_t)(b*400 + s))*512 + c];
#pragma unroll
    for (int tt = 0; tt < 16; ++tt) acc[tt] += prl[tt][s]*ev;
  }
  if (sg == 1) {
#pragma unroll
    for (int tt = 0; tt < 16; ++tt) redbuf[tt][tid & 127] = acc[tt];
  }
  __syncthreads();
  if (sg == 0) {
#pragma unroll
    for (int tt = 0; tt < 16; ++tt)
      A1[((size_t)(tt*8+b))*1024 + 512 + c] = acc[tt] + redbuf[tt][tid & 127];
  }
}

// Epilogue: pgen all (t,b) + out1/2/3/5 + rowsum zero
__global__ __launch_bounds__(256) void e_pgen(
    const float* __restrict__ A1, const float* __restrict__ c_cur,
    const float* __restrict__ emb, const float* __restrict__ context,
    const float* __restrict__ pw, const float* __restrict__ q,
    const float* __restrict__ qb, float* __restrict__ pgen,
    float* __restrict__ rowsum, float* __restrict__ out)
{
  int blk = blockIdx.x, tid = threadIdx.x;
  if (blk < 128) {
    int m = blk, t = m >> 3, b = m & 7;
    const float* ctxT = A1 + (size_t)m*1024 + 512;
    const float* hT   = A1 + (size_t)m*1024;
    const float* embp = emb + (size_t)(b*16+t)*128;
    const float* ctxP = t ? (A1 + ((size_t)((t-1)*8+b))*1024 + 512) : (context + b*512);
    float acc = 0.f;
    for (int k = tid; k < 512; k += 256)
      acc += pw[k]*ctxT[k] + pw[512+k]*hT[k] + q[128+k]*ctxP[k];
    if (tid < 128) acc += q[tid]*embp[tid];
    for (int off = 32; off > 0; off >>= 1) acc += __shfl_down(acc, off);
    __shared__ float red[4];
    if (!(tid & 63)) red[tid>>6] = acc;
    __syncthreads();
    if (tid == 0) {
      float pg = sigm(red[0]+red[1]+red[2]+red[3] + qb[0]);
      pgen[m] = pg;
      if (t == 15) out[O5 + b] = pg;
    }
  } else if (blk == 128) {
    for (int i = tid; i < 4096; i += 256) {
      int b = i >> 9, j = i & 511;
      out[O1 + i] = A1[((size_t)(120+b))*1024 + 512 + j];
    }
  } else if (blk == 129) {
    for (int i = tid; i < 4096; i += 256) {
      int b = i >> 9, j = i & 511;
      out[O2 + i] = A1[((size_t)(120+b))*1024 + j];
    }
  } else if (blk == 130) {
    for (int i = tid; i < 4096; i += 256) out[O3 + i] = c_cur[i];
  } else {
    if (tid < 128) rowsum[tid] = 0.f;
  }
}

// scale by pg/rowsum + OOV cols
__global__ __launch_bounds__(256) void k_scale(
    float* __restrict__ out, const float* __restrict__ pgen,
    const float* __restrict__ rowsum, const float* __restrict__ ez)
{
  int orow = blockIdx.x, cy = blockIdx.y, tid = threadIdx.x;
  int b = orow >> 4, t = orow & 15;
  float sc = pgen[t*8+b] / rowsum[orow];
  int c0 = cy*6256;
  int c1 = (cy == 7) ? VE : c0 + 6256;
  float* row = out + (size_t)orow*VE;
  for (int c = c0 + tid*4; c < c1; c += 1024) {
    if (c + 4 <= VV && c + 4 <= c1) {
      float4 v = *(float4*)(row + c);
      v.x *= sc; v.y *= sc; v.z *= sc; v.w *= sc;
      *(float4*)(row + c) = v;
    } else {
      for (int e = 0; e < 4; ++e) {
        int cc2 = c + e;
        if (cc2 < c1) row[cc2] = (cc2 < VV) ? row[cc2]*sc : ez[b*OOVn + cc2 - VV];
      }
    }
  }
}

// copy-mechanism scatter
__global__ __launch_bounds__(256) void k_scatter(
    float* __restrict__ out, const float* __restrict__ pgen,
    const int* __restrict__ extidx)
{
  int m = blockIdx.x, tid = threadIdx.x;  // m = t*8+b
  int b = m & 7, t = m >> 3;
  float* row = out + ((size_t)(b*TT + t))*VE;
  float onem = 1.0f - pgen[m];
  const float* pr = out + O4 + ((size_t)(b*TT+t))*SS;
  for (int s = tid; s < SS; s += 256) {
    int ix = extidx[b*SS + s];
    atomicAdd(&row[ix], onem * pr[s]);
  }
}

extern "C" void kernel_launch(void* const* d_in, const int* in_sizes, int n_in,
                              void* d_out, int out_size, void* d_ws, size_t ws_size,
                              hipStream_t stream)
{
  (void)in_sizes; (void)n_in; (void)out_size; (void)ws_size;
  const float* emb      = (const float*)d_in[0];
  const float* context  = (const float*)d_in[1];
  const float* h0       = (const float*)d_in[2];
  const float* c0       = (const float*)d_in[3];
  const float* enc      = (const float*)d_in[4];
  const float* masks    = (const float*)d_in[5];
  const float* ez       = (const float*)d_in[6];
  const int*   extidx   = (const int*)d_in[7];
  const float* coverage = (const float*)d_in[8];
  const float* wih      = (const float*)d_in[9];
  const float* whh      = (const float*)d_in[10];
  const float* bih      = (const float*)d_in[11];
  const float* bhh      = (const float*)d_in[12];
  const float* covw     = (const float*)d_in[13];
  const float* ew       = (const float*)d_in[14];
  const float* eb       = (const float*)d_in[15];
  const float* vvec     = (const float*)d_in[16];
  const float* xw       = (const float*)d_in[17];
  const float* xb       = (const float*)d_in[18];
  const float* aw       = (const float*)d_in[19];
  const float* ab       = (const float*)d_in[20];
  const float* vw       = (const float*)d_in[21];
  const float* vb       = (const float*)d_in[22];
  const float* pw       = (const float*)d_in[23];
  const float* pb       = (const float*)d_in[24];
  float* out = (float*)d_out;

  float* ws = (float*)d_ws;
  float* A1       = ws;                 // 128 x 1024 [h | ctx]
  float* c_cur    = ws + 131072;        // 4096
  unsigned short* attnd_bf = (unsigned short*)(ws + 139264);  // 128x512
  float* pgen     = ws + 172032;        // 128
  float* gb       = ws + 172160;        // 2048
  float* q        = ws + 174208;        // 640
  float* qb       = ws + 174848;        // 1
  float* d1       = ws + 174852;        // 128
  float* d2       = ws + 174980;        // 128
  float* rowsum   = ws + 175108;        // 128

  unsigned short* G     = (unsigned short*)(out + G_OFF);
  unsigned short* ewhb  = (unsigned short*)(out + EWHB_OFF);
  unsigned short* encG  = (unsigned short*)(out + ENCG_OFF);
  unsigned short* encpb = (unsigned short*)(out + ENCP_OFF);
  float*          PM    = out + PM_OFF;

  // Prologue
  p_wx<<<1280, 256, 0, stream>>>(wih, whh, xw, ew, G, ewhb);
  p_small<<<12, 256, 0, stream>>>(wih, bih, bhh, xb, xw, pw, pb, gb, q, qb, d1, d2);
  // encG[b] = Wx_ctx @ enc_b^T  (A = G cols 128..639, bf16; batched over b)
  gemm_direct<1,1,0,0><<<dim3(16,7,8), 256, 0, stream>>>(
      (const void*)(G + 128), 1152, enc, 512, (const float*)nullptr,
      (void*)encG, 400L, 400, 512, (long)400*512, (long)2048*400, nullptr);
  // encp = bf16(enc @ energy_w[:,512:].T)
  gemm_direct<0,1,0,0><<<dim3(25,8,1), 256, 0, stream>>>(
      (const void*)enc, 512, ew + 512, 1024, (const float*)nullptr,
      (void*)encpb, 512L, 512, 512, 0L, 0L, nullptr);

  for (int t = 0; t < TT; ++t) {
    s1g<<<256, 256, 0, stream>>>(G, encG, gb, emb, context, h0, c0, coverage,
                                 PM, d1, d2, A1, c_cur, out, t);
    s23<<<64, 256, 0, stream>>>(ewhb, eb, A1, encpb, vvec, covw, masks,
                                coverage, out + O6, PM, d1, d2, t);
  }

  ctx_all<<<32, 256, 0, stream>>>(PM, d1, d2, enc, A1, out);
  e_pgen<<<132, 256, 0, stream>>>(A1, c_cur, emb, context, pw, q, qb, pgen, rowsum, out);
  // attnd_bf = bf16([h|ctx] @ attnd_w.T + attnd_b)
  gemm_direct<0,1,0,0><<<dim3(1,8,1), 256, 0, stream>>>(
      (const void*)A1, 1024, aw, 1024, ab,
      (void*)attnd_bf, 512L, 512, 1024, 0L, 0L, nullptr);
  // logits: exp(attnd_bf @ vocab_w.T + vb) -> out rows (b*16+t), + rowsums
  gemm_direct<1,0,1,1><<<dim3(1,782,1), 256, 0, stream>>>(
      (const void*)attnd_bf, 512, vw, 512, vb,
      (void*)out, (long)VE, VV, 512, 0L, 0L, rowsum);
  k_scale<<<dim3(128,8), 256, 0, stream>>>(out, pgen, rowsum, ez);
  k_scatter<<<128, 256, 0, stream>>>(out, pgen, extidx);
}

// Round 6
// 1092.160 us; speedup vs baseline: 1.1092x; 1.1092x over previous
//
#include <hip/hip_runtime.h>
#include <math.h>

#define BB 8
#define TT 16
#define SS 400
#define HH 512
#define EE 128
#define VV 50000
#define VE 50050
#define OOVn 50

// output offsets (floats)
#define O1 6406400
#define O2 6410496
#define O3 6414592
#define O4 6418688
#define O5 6469888
#define O6 6469896

// scratch inside out0 logits region (float offsets; dead until gemm_logits)
#define G_OFF    0          // 2048x1152 ushort = 1,179,648 f
#define EWHB_OFF 1179648    // 512x512  ushort =   131,072 f -> ends 1,310,720
#define ENCG_OFF 1310720    // 8x2048x400 ushort = 3,276,800 f -> ends 4,587,520
#define ENCP_OFF 4600000    // 3200x512 ushort = 819,200 f -> ends 5,419,200
#define PM_OFF   5700000    // 16x8x400 fp32 = 51,200 f -> ends 5,751,200

typedef __attribute__((ext_vector_type(4))) float floatx4;
typedef __attribute__((ext_vector_type(8))) short short8;
typedef __attribute__((ext_vector_type(8))) unsigned short ushort8_t;
typedef __attribute__((ext_vector_type(4))) unsigned short ushort4_t;

__device__ __forceinline__ float sigm(float x){ return 1.0f/(1.0f+__expf(-x)); }
__device__ __forceinline__ float ftanh(float x){
  float e = __expf(2.0f*x); return 1.0f - 2.0f/(e + 1.0f);
}
__device__ __forceinline__ unsigned short f2bf(float f){
  union { float f; unsigned int u; } v; v.f = f;
  unsigned int u = v.u;
  return (unsigned short)((u + 0x7FFFu + ((u >> 16) & 1u)) >> 16);
}
__device__ __forceinline__ float bfu(unsigned short u){
  union { unsigned int i; float f; } v; v.i = ((unsigned int)u) << 16; return v.f;
}

// ---------------------------------------------------------------------------
// Staged GEMM, 128(M) x 128(N) tile, register-batch staging + LDS + explicit
// prefetch: chunk k+1's global loads issue before chunk k's MFMAs so they
// drain during compute + barrier. fp32 (or bf16) in, bf16 MFMA, out fp32/bf16.
// M multiple of 128; N ragged-guarded; K multiple of 64.
// ABF: A is bf16 (ushort, leading dim lda). OBF: bf16 out.
// EXPO: out = exp(v) fp32 + per-row sums into rowsum[128] (M must be 128).
// PERM: C row = (m&7)*16 + (m>>3)  (m = t*8+b -> b*16+t), M must be 128.
// ---------------------------------------------------------------------------
template<int ABF, int OBF, int EXPO, int PERM>
__global__ __launch_bounds__(256) void gemm128(
    const void* __restrict__ Ap, int lda,
    const float* __restrict__ Bm, int ldb,
    const float* __restrict__ bias,
    void* __restrict__ Cp, long ldc,
    int N, int K, long bsB, long bsC,
    float* __restrict__ rowsum)
{
  __shared__ unsigned short Ash[128*72];
  __shared__ unsigned short Bsh[128*72];
  __shared__ float rowpart[128];
  int tid = threadIdx.x;
  int mbase = blockIdx.x * 128;
  int nbase = blockIdx.y * 128;
  const float* Bz = Bm + (long)blockIdx.z * bsB;
  int wave = tid >> 6, lane = tid & 63;
  int wm = (wave & 1)*64, wn = (wave >> 1)*64;
  int fl = lane & 15, quad = lane >> 4;

  floatx4 acc[4][4];
#pragma unroll
  for (int i=0;i<4;i++)
#pragma unroll
    for(int j=0;j<4;j++) acc[i][j] = (floatx4)(0.0f);
  if (EXPO && tid < 128) rowpart[tid] = 0.f;

  ushort8_t rau[4];
  float4 raf[8];
  float4 rbf[8];

  // initial staging loads (chunk 0)
  if (ABF) {
    const unsigned short* Au = (const unsigned short*)Ap;
#pragma unroll
    for (int i=0;i<4;i++){
      int idx = tid + i*256;
      int row = idx >> 3, c8 = (idx & 7) << 3;
      rau[i] = *(const ushort8_t*)(Au + (size_t)(mbase+row)*lda + c8);
    }
  } else {
    const float* Af = (const float*)Ap;
#pragma unroll
    for (int i=0;i<8;i++){
      int idx = tid + i*256;
      int row = idx >> 4, c4 = (idx & 15) << 2;
      raf[i] = *(const float4*)(Af + (size_t)(mbase+row)*lda + c4);
    }
  }
#pragma unroll
  for (int i=0;i<8;i++){
    int idx = tid + i*256;
    int row = idx >> 4, c4 = (idx & 15) << 2;
    int gn = nbase + row;
    if (gn < N) rbf[i] = *(const float4*)(Bz + (size_t)gn*ldb + c4);
    else { rbf[i].x=0.f; rbf[i].y=0.f; rbf[i].z=0.f; rbf[i].w=0.f; }
  }

  for (int kc = 0; kc < K; kc += 64) {
    __syncthreads();   // prev chunk's frag reads done
    if (ABF) {
#pragma unroll
      for (int i=0;i<4;i++){
        int idx = tid + i*256;
        int o = (idx >> 3)*72 + ((idx & 7) << 3);
        *(ushort8_t*)&Ash[o] = rau[i];
      }
    } else {
#pragma unroll
      for (int i=0;i<8;i++){
        int idx = tid + i*256;
        int o = (idx >> 4)*72 + ((idx & 15) << 2);
        Ash[o+0]=f2bf(raf[i].x); Ash[o+1]=f2bf(raf[i].y); Ash[o+2]=f2bf(raf[i].z); Ash[o+3]=f2bf(raf[i].w);
      }
    }
#pragma unroll
    for (int i=0;i<8;i++){
      int idx = tid + i*256;
      int o = (idx >> 4)*72 + ((idx & 15) << 2);
      Bsh[o+0]=f2bf(rbf[i].x); Bsh[o+1]=f2bf(rbf[i].y); Bsh[o+2]=f2bf(rbf[i].z); Bsh[o+3]=f2bf(rbf[i].w);
    }
    __syncthreads();
    // prefetch next chunk BEFORE MFMAs: loads drain during compute + barrier
    int kn = kc + 64;
    if (kn < K) {
      if (ABF) {
        const unsigned short* Au = (const unsigned short*)Ap;
#pragma unroll
        for (int i=0;i<4;i++){
          int idx = tid + i*256;
          int row = idx >> 3, c8 = (idx & 7) << 3;
          rau[i] = *(const ushort8_t*)(Au + (size_t)(mbase+row)*lda + kn + c8);
        }
      } else {
        const float* Af = (const float*)Ap;
#pragma unroll
        for (int i=0;i<8;i++){
          int idx = tid + i*256;
          int row = idx >> 4, c4 = (idx & 15) << 2;
          raf[i] = *(const float4*)(Af + (size_t)(mbase+row)*lda + kn + c4);
        }
      }
#pragma unroll
      for (int i=0;i<8;i++){
        int idx = tid + i*256;
        int row = idx >> 4, c4 = (idx & 15) << 2;
        int gn = nbase + row;
        if (gn < N) rbf[i] = *(const float4*)(Bz + (size_t)gn*ldb + kn + c4);
        else { rbf[i].x=0.f; rbf[i].y=0.f; rbf[i].z=0.f; rbf[i].w=0.f; }
      }
    }
#pragma unroll
    for (int ks=0; ks<2; ++ks){
      short8 af[4], bfr[4];
      int ko = ks*32 + quad*8;
#pragma unroll
      for (int i=0;i<4;i++) af[i]  = *(const short8*)&Ash[(wm + i*16 + fl)*72 + ko];
#pragma unroll
      for (int j=0;j<4;j++) bfr[j] = *(const short8*)&Bsh[(wn + j*16 + fl)*72 + ko];
#pragma unroll
      for (int i=0;i<4;i++)
#pragma unroll
        for (int j=0;j<4;j++)
          acc[i][j] = __builtin_amdgcn_mfma_f32_16x16x32_bf16(af[i], bfr[j], acc[i][j], 0,0,0);
    }
  }

  if (EXPO) __syncthreads();
#pragma unroll
  for (int i=0;i<4;i++){
#pragma unroll
    for (int r=0;r<4;r++){
      int mg = mbase + wm + i*16 + quad*4 + r;
      int orow = PERM ? ((mg & 7)*16 + (mg >> 3)) : mg;
      float rs = 0.f;
#pragma unroll
      for (int j=0;j<4;j++){
        int nc = nbase + wn + j*16 + fl;
        if (nc >= N) continue;
        float v = acc[i][j][r] + (bias ? bias[nc] : 0.f);
        long ci = (long)orow*ldc + nc + (long)blockIdx.z*bsC;
        if (EXPO) {
          float e = __expf(v);
          ((float*)Cp)[ci] = e;
          rs += e;
        } else if (OBF) {
          ((unsigned short*)Cp)[ci] = f2bf(v);
        } else {
          ((float*)Cp)[ci] = v;
        }
      }
      if (EXPO) atomicAdd(&rowpart[mg & 127], rs);
    }
  }
  if (EXPO) {
    __syncthreads();
    if (tid < 128) {
      int orow = (tid & 7)*16 + (tid >> 3);
      atomicAdd(&rowsum[orow], rowpart[tid]);
    }
  }
}

// ---------------------------------------------------------------------------
// Prologue P1: G = [Wx = W_ih@xctx_w (640) | W_hh (512)] bf16 (2048x1152);
// plus ewhb = bf16(energy_w[:, :512]).  grid 1280.
// ---------------------------------------------------------------------------
__global__ __launch_bounds__(256) void p_wx(const float* __restrict__ wih,
    const float* __restrict__ whh, const float* __restrict__ xcw,
    const float* __restrict__ ew,
    unsigned short* __restrict__ G, unsigned short* __restrict__ ewhb)
{
  int blk = blockIdx.x, tid = threadIdx.x;
  if (blk < 640) {
    int rt = blk / 10, ct = blk % 10;
    __shared__ float wl[32*128];
    __shared__ float xl[128*64];
    for (int i = tid; i < 4096; i += 256) {
      int r = i >> 7, k = i & 127;
      wl[i] = wih[(size_t)(rt*32+r)*128 + k];
    }
    for (int i = tid; i < 8192; i += 256) {
      int e = i >> 6, c = i & 63;
      xl[i] = xcw[(size_t)e*640 + ct*64 + c];
    }
    __syncthreads();
    for (int o = tid; o < 2048; o += 256) {
      int r = o >> 6, c = o & 63;
      float acc = 0.f;
      for (int e = 0; e < 128; ++e) acc += wl[r*128+e]*xl[e*64+c];
      G[(size_t)(rt*32+r)*1152 + ct*64 + c] = f2bf(acc);
    }
  } else if (blk < 1152) {
    int idx = blk - 640;  // 0..511
    for (int q = 0; q < 2; ++q) {
      int n = idx*2048 + q*1024 + tid*4;
      int r = n >> 9, k = n & 511;
      float4 v = *(const float4*)(whh + n);
      ushort4_t s; s[0]=f2bf(v.x); s[1]=f2bf(v.y); s[2]=f2bf(v.z); s[3]=f2bf(v.w);
      *(ushort4_t*)(G + (size_t)r*1152 + 640 + k) = s;
    }
  } else {
    int idx = blk - 1152;  // 0..127
    for (int q = 0; q < 2; ++q) {
      size_t n = (size_t)idx*2048 + q*1024 + tid*4;
      int p = (int)(n >> 9), k = (int)(n & 511);
      float4 v = *(const float4*)(ew + (size_t)p*1024 + k);
      ushort4_t s; s[0]=f2bf(v.x); s[1]=f2bf(v.y); s[2]=f2bf(v.z); s[3]=f2bf(v.w);
      *(ushort4_t*)(ewhb + n) = s;
    }
  }
}

// Prologue P2: gb = b_ih+b_hh+W_ih@xb ; q = xctx_w^T@pw_x ; qb ; zero d1/d2
__global__ __launch_bounds__(256) void p_small(const float* __restrict__ wih,
    const float* __restrict__ bih, const float* __restrict__ bhh,
    const float* __restrict__ xb, const float* __restrict__ xcw,
    const float* __restrict__ pw, const float* __restrict__ pb,
    float* __restrict__ gb, float* __restrict__ q, float* __restrict__ qb,
    float* __restrict__ d1, float* __restrict__ d2)
{
  int blk = blockIdx.x, tid = threadIdx.x;
  if (blk < 8) {
    __shared__ float xbl[128];
    if (tid < 128) xbl[tid] = xb[tid];
    __syncthreads();
    int r = blk*256 + tid;
    const float* wr = wih + (size_t)r*128;
    float acc = bih[r] + bhh[r];
    for (int e = 0; e < 128; ++e) acc += wr[e]*xbl[e];
    gb[r] = acc;
  } else if (blk < 11) {
    int o = (blk-8)*256 + tid;
    if (o < 640) {
      float acc = 0.f;
      for (int e = 0; e < 128; ++e) acc += pw[1024+e]*xcw[(size_t)e*640 + o];
      q[o] = acc;
    }
  } else {
    if (tid == 0) {
      float acc = 0.f;
      for (int e = 0; e < 128; ++e) acc += pw[1024+e]*xb[e];
      qb[0] = acc + pb[0];
    }
    if (tid < 128) { d1[tid] = 0.f; d2[tid] = 0.f; }
  }
}

// ---------------------------------------------------------------------------
// S1: gates[r,b] = gb + G_emb@emb + G_h@h(t-1) + ctx-part -> LSTM -> h(t),c(t)
//   ctx-part: t==0: G_ctx @ context;  t>=1: sum_s probs(t-1)[s] * encG[b,r,s]
// Also (blk<8, t>=1): writes out4/out6 for step t-1.
// ---------------------------------------------------------------------------
__global__ __launch_bounds__(256) void s1g(
    const unsigned short* __restrict__ G, const unsigned short* __restrict__ encG,
    const float* __restrict__ gb,
    const float* __restrict__ emb, const float* __restrict__ context,
    const float* __restrict__ h0, const float* __restrict__ c0,
    const float* __restrict__ coverage,
    const float* __restrict__ PM, const float* __restrict__ d1,
    const float* __restrict__ d2,
    float* __restrict__ A1, float* __restrict__ c_cur,
    float* __restrict__ out, int t)
{
  __shared__ float ueh[8][644];   // [emb(128) | h(512)]
  __shared__ float uc[8][516];    // t==0: context(512) ; t>=1: probs(400)
  __shared__ float part[256];
  __shared__ float gl[64];
  __shared__ float invs[8];
  int tid = threadIdx.x, blk = blockIdx.x;

  if (t >= 1 && tid < 8)
    invs[tid] = 1.0f / (d2[(t-1)*8 + tid] + 1e-12f*d1[(t-1)*8 + tid]);
  __syncthreads();

  for (int i = 0; i < 5; ++i) {
    int slot = i*256 + tid;
    int b = slot / 160, sl = slot - b*160;
    if (sl < 32) {
      *(float4*)&ueh[b][sl*4] = *(const float4*)(emb + (size_t)(b*16+t)*128 + sl*4);
    } else {
      int qq = sl - 32;
      const float* hsrc = t ? (A1 + ((size_t)((t-1)*8+b))*1024) : (h0 + b*512);
      *(float4*)&ueh[b][128 + qq*4] = *(const float4*)(hsrc + qq*4);
    }
  }
  if (t == 0) {
    for (int i = 0; i < 4; ++i) {
      int slot = i*256 + tid;
      int b = slot >> 7, sl = slot & 127;
      *(float4*)&uc[b][sl*4] = *(const float4*)(context + b*512 + sl*4);
    }
  } else {
    const float* pmsrc = PM + (size_t)(t-1)*3200;
    for (int i = 0; i < 4; ++i) {
      int slot = i*256 + tid;
      if (slot < 800) {
        int b = slot / 100, sl = slot - b*100;
        float4 p4 = *(const float4*)(pmsrc + b*400 + sl*4);
        float iv = invs[b];
        p4.x *= iv; p4.y *= iv; p4.z *= iv; p4.w *= iv;
        *(float4*)&uc[b][sl*4] = p4;
      }
    }
  }
  __syncthreads();

  if (t >= 1 && blk < 8) {
    int b = blk;
    const float* covprev = (t == 1) ? (coverage + b*400)
                                    : (out + O6 + ((size_t)(b*16 + t-2))*400);
    size_t o = ((size_t)(b*16 + t-1))*400;
    for (int s = tid; s < 400; s += 256) {
      float pr = uc[b][s];
      out[O4 + o + s] = pr;
      out[O6 + o + s] = covprev[s] + pr;
    }
  }

  int dot = tid >> 2, kq = tid & 3;
  int rr = dot >> 3, b = dot & 7;
  int gate = rr >> 1, jj = rr & 1;
  int r = gate*512 + blk*2 + jj;
  const unsigned short* gr = G + (size_t)r*1152;
  float acc = 0.f;
  {
    const unsigned short* gp = gr + kq*8;
    const float* up = &ueh[b][kq*8];
#pragma unroll
    for (int i = 0; i < 4; ++i) {
      ushort8_t w8 = *(const ushort8_t*)(gp + i*32);
      float4 u0 = *(const float4*)(up + i*32);
      float4 u1 = *(const float4*)(up + i*32 + 4);
      acc += bfu(w8[0])*u0.x + bfu(w8[1])*u0.y + bfu(w8[2])*u0.z + bfu(w8[3])*u0.w
           + bfu(w8[4])*u1.x + bfu(w8[5])*u1.y + bfu(w8[6])*u1.z + bfu(w8[7])*u1.w;
    }
  }
  {
    const unsigned short* gp = gr + 640 + kq*8;
    const float* up = &ueh[b][128 + kq*8];
#pragma unroll 4
    for (int i = 0; i < 16; ++i) {
      ushort8_t w8 = *(const ushort8_t*)(gp + i*32);
      float4 u0 = *(const float4*)(up + i*32);
      float4 u1 = *(const float4*)(up + i*32 + 4);
      acc += bfu(w8[0])*u0.x + bfu(w8[1])*u0.y + bfu(w8[2])*u0.z + bfu(w8[3])*u0.w
           + bfu(w8[4])*u1.x + bfu(w8[5])*u1.y + bfu(w8[6])*u1.z + bfu(w8[7])*u1.w;
    }
  }
  if (t == 0) {
    const unsigned short* gp = gr + 128 + kq*8;
    const float* up = &uc[b][kq*8];
#pragma unroll 4
    for (int i = 0; i < 16; ++i) {
      ushort8_t w8 = *(const ushort8_t*)(gp + i*32);
      float4 u0 = *(const float4*)(up + i*32);
      float4 u1 = *(const float4*)(up + i*32 + 4);
      acc += bfu(w8[0])*u0.x + bfu(w8[1])*u0.y + bfu(w8[2])*u0.z + bfu(w8[3])*u0.w
           + bfu(w8[4])*u1.x + bfu(w8[5])*u1.y + bfu(w8[6])*u1.z + bfu(w8[7])*u1.w;
    }
  } else {
    const unsigned short* gp = encG + ((size_t)(b*2048 + r))*400 + kq*8;
    const float* up = &uc[b][kq*8];
#pragma unroll 4
    for (int i = 0; i < 12; ++i) {
      ushort8_t w8 = *(const ushort8_t*)(gp + i*32);
      float4 u0 = *(const float4*)(up + i*32);
      float4 u1 = *(const float4*)(up + i*32 + 4);
      acc += bfu(w8[0])*u0.x + bfu(w8[1])*u0.y + bfu(w8[2])*u0.z + bfu(w8[3])*u0.w
           + bfu(w8[4])*u1.x + bfu(w8[5])*u1.y + bfu(w8[6])*u1.z + bfu(w8[7])*u1.w;
    }
    if (kq < 2) {
      ushort8_t w8 = *(const ushort8_t*)(gp + 12*32);
      float4 u0 = *(const float4*)(up + 12*32);
      float4 u1 = *(const float4*)(up + 12*32 + 4);
      acc += bfu(w8[0])*u0.x + bfu(w8[1])*u0.y + bfu(w8[2])*u0.z + bfu(w8[3])*u0.w
           + bfu(w8[4])*u1.x + bfu(w8[5])*u1.y + bfu(w8[6])*u1.z + bfu(w8[7])*u1.w;
    }
  }
  part[tid] = acc;
  __syncthreads();
  if (tid < 64) {
    int rr2 = tid >> 3;
    int r2 = (rr2 >> 1)*512 + blk*2 + (rr2 & 1);
    gl[tid] = part[tid*4] + part[tid*4+1] + part[tid*4+2] + part[tid*4+3] + gb[r2];
  }
  __syncthreads();
  if (tid < 16) {
    int jj2 = tid >> 3, b2 = tid & 7;
    float gi = gl[(0*2+jj2)*8 + b2];
    float gf = gl[(1*2+jj2)*8 + b2];
    float gg = gl[(2*2+jj2)*8 + b2];
    float go = gl[(3*2+jj2)*8 + b2];
    int j = blk*2 + jj2;
    float cp = t ? c_cur[b2*512+j] : c0[b2*512+j];
    float cn = sigm(gf)*cp + sigm(gi)*ftanh(gg);
    float hn = sigm(go)*ftanh(cn);
    c_cur[b2*512+j] = cn;
    A1[((size_t)(t*8+b2))*1024 + j] = hn;
  }
}

// ---------------------------------------------------------------------------
// S23: fused hp + energy + exp. 64 blocks (8 b x 8 s-chunks of 50).
// ---------------------------------------------------------------------------
__global__ __launch_bounds__(256) void s23(
    const unsigned short* __restrict__ ewhb, const float* __restrict__ eb,
    const float* __restrict__ A1, const unsigned short* __restrict__ encpb,
    const float* __restrict__ vvec, const float* __restrict__ covw,
    const float* __restrict__ masks, const float* __restrict__ coverage,
    const float* __restrict__ out6v, float* __restrict__ PM,
    float* __restrict__ d1, float* __restrict__ d2, int t)
{
  int tid = threadIdx.x;
  int b = blockIdx.x >> 3, sc = blockIdx.x & 7;
  __shared__ float hl[512];
  __shared__ float hps[512];
  __shared__ float red1[4], red2[4];
  for (int k = tid; k < 512; k += 256) hl[k] = A1[((size_t)(t*8+b))*1024 + k];
  __syncthreads();
#pragma unroll
  for (int pi = 0; pi < 2; ++pi) {
    int p = tid + pi*256;
    const unsigned short* wp = ewhb + (size_t)p*512;
    float acc = 0.f;
#pragma unroll 4
    for (int k = 0; k < 512; k += 8) {
      ushort8_t w8 = *(const ushort8_t*)(wp + k);
      float4 u0 = *(const float4*)(hl + k);
      float4 u1 = *(const float4*)(hl + k + 4);
      acc += bfu(w8[0])*u0.x + bfu(w8[1])*u0.y + bfu(w8[2])*u0.z + bfu(w8[3])*u0.w
           + bfu(w8[4])*u1.x + bfu(w8[5])*u1.y + bfu(w8[6])*u1.z + bfu(w8[7])*u1.w;
    }
    hps[p] = eb[p] + acc;
  }
  __syncthreads();
  int w = tid >> 6, lane = tid & 63;
  int h0i = lane*8;
  float hpv[8], vv[8], cw[8];
  {
    float4 a0 = *(const float4*)&hps[h0i], a1 = *(const float4*)&hps[h0i+4];
    hpv[0]=a0.x; hpv[1]=a0.y; hpv[2]=a0.z; hpv[3]=a0.w;
    hpv[4]=a1.x; hpv[5]=a1.y; hpv[6]=a1.z; hpv[7]=a1.w;
    float4 v0 = *(const float4*)(vvec+h0i), v1 = *(const float4*)(vvec+h0i+4);
    vv[0]=v0.x; vv[1]=v0.y; vv[2]=v0.z; vv[3]=v0.w;
    vv[4]=v1.x; vv[5]=v1.y; vv[6]=v1.z; vv[7]=v1.w;
    float4 c0v = *(const float4*)(covw+h0i), c1v = *(const float4*)(covw+h0i+4);
    cw[0]=c0v.x; cw[1]=c0v.y; cw[2]=c0v.z; cw[3]=c0v.w;
    cw[4]=c1v.x; cw[5]=c1v.y; cw[6]=c1v.z; cw[7]=c1v.w;
  }
  const float* covp = t ? (out6v + ((size_t)(b*16 + t-1))*400) : (coverage + b*400);
  float a1s = 0.f, a2s = 0.f;
  for (int sl = w; sl < 50; sl += 4) {
    int s = sc*50 + sl;
    float cv = covp[s];
    const unsigned short* ep = encpb + ((size_t)(b*400+s))*512 + h0i;
    ushort8_t e8 = *(const ushort8_t*)ep;
    float acc = 0.f;
#pragma unroll
    for (int i = 0; i < 8; ++i)
      acc += ftanh(hpv[i] + bfu(e8[i]) + cv*cw[i]) * vv[i];
    for (int off = 32; off > 0; off >>= 1) acc += __shfl_down(acc, off);
    if (lane == 0) {
      float pe = __expf(acc);
      float pmv = pe * masks[b*400 + s];
      PM[(size_t)t*3200 + b*400 + s] = pmv;
      a1s += pe; a2s += pmv;
    }
  }
  if (lane == 0) { red1[w] = a1s; red2[w] = a2s; }
  __syncthreads();
  if (tid == 0) {
    atomicAdd(&d1[t*8+b], red1[0]+red1[1]+red1[2]+red1[3]);
    atomicAdd(&d2[t*8+b], red2[0]+red2[1]+red2[2]+red2[3]);
  }
}

// ctx for ALL t (post-loop): A1 ctx cols; also out4/out6 for t=15.
__global__ __launch_bounds__(256) void ctx_all(
    const float* __restrict__ PM, const float* __restrict__ d1,
    const float* __restrict__ d2, const float* __restrict__ enc,
    float* __restrict__ A1, float* __restrict__ out)
{
  int tid = threadIdx.x;
  int b = blockIdx.x >> 2, cc = blockIdx.x & 3;
  __shared__ float prl[16][400];
  __shared__ float redbuf[16][128];
  __shared__ float invs[16];
  if (tid < 16) invs[tid] = 1.0f / (d2[tid*8+b] + 1e-12f*d1[tid*8+b]);
  __syncthreads();
  for (int i = 0; i < 7; ++i) {
    int slot = i*256 + tid;
    if (slot < 1600) {
      int tt = slot / 100, sl = slot - tt*100;
      float4 p4 = *(const float4*)(PM + (size_t)tt*3200 + b*400 + sl*4);
      float iv = invs[tt];
      p4.x *= iv; p4.y *= iv; p4.z *= iv; p4.w *= iv;
      *(float4*)&prl[tt][sl*4] = p4;
    }
  }
  __syncthreads();
  if (cc == 0) {
    size_t o15 = ((size_t)(b*16 + 15))*400;
    size_t o14 = ((size_t)(b*16 + 14))*400;
    for (int s = tid; s < 400; s += 256) {
      float pr = prl[15][s];
      out[O4 + o15 + s] = pr;
      out[O6 + o15 + s] = out[O6 + o14 + s] + pr;
    }
  }
  int c = cc*128 + (tid & 127);
  int sg = tid >> 7;
  float acc[16];
#pragma unroll
  for (int tt = 0; tt < 16; ++tt) acc[tt] = 0.f;
  for (int s = sg*200; s < sg*200 + 200; ++s) {
    float ev = enc[((size_t)(b*400 + s))*512 + c];
#pragma unroll
    for (int tt = 0; tt < 16; ++tt) acc[tt] += prl[tt][s]*ev;
  }
  if (sg == 1) {
#pragma unroll
    for (int tt = 0; tt < 16; ++tt) redbuf[tt][tid & 127] = acc[tt];
  }
  __syncthreads();
  if (sg == 0) {
#pragma unroll
    for (int tt = 0; tt < 16; ++tt)
      A1[((size_t)(tt*8+b))*1024 + 512 + c] = acc[tt] + redbuf[tt][tid & 127];
  }
}

// Epilogue: pgen all (t,b) + out1/2/3/5 + rowsum zero
__global__ __launch_bounds__(256) void e_pgen(
    const float* __restrict__ A1, const float* __restrict__ c_cur,
    const float* __restrict__ emb, const float* __restrict__ context,
    const float* __restrict__ pw, const float* __restrict__ q,
    const float* __restrict__ qb, float* __restrict__ pgen,
    float* __restrict__ rowsum, float* __restrict__ out)
{
  int blk = blockIdx.x, tid = threadIdx.x;
  if (blk < 128) {
    int m = blk, t = m >> 3, b = m & 7;
    const float* ctxT = A1 + (size_t)m*1024 + 512;
    const float* hT   = A1 + (size_t)m*1024;
    const float* embp = emb + (size_t)(b*16+t)*128;
    const float* ctxP = t ? (A1 + ((size_t)((t-1)*8+b))*1024 + 512) : (context + b*512);
    float acc = 0.f;
    for (int k = tid; k < 512; k += 256)
      acc += pw[k]*ctxT[k] + pw[512+k]*hT[k] + q[128+k]*ctxP[k];
    if (tid < 128) acc += q[tid]*embp[tid];
    for (int off = 32; off > 0; off >>= 1) acc += __shfl_down(acc, off);
    __shared__ float red[4];
    if (!(tid & 63)) red[tid>>6] = acc;
    __syncthreads();
    if (tid == 0) {
      float pg = sigm(red[0]+red[1]+red[2]+red[3] + qb[0]);
      pgen[m] = pg;
      if (t == 15) out[O5 + b] = pg;
    }
  } else if (blk == 128) {
    for (int i = tid; i < 4096; i += 256) {
      int b = i >> 9, j = i & 511;
      out[O1 + i] = A1[((size_t)(120+b))*1024 + 512 + j];
    }
  } else if (blk == 129) {
    for (int i = tid; i < 4096; i += 256) {
      int b = i >> 9, j = i & 511;
      out[O2 + i] = A1[((size_t)(120+b))*1024 + j];
    }
  } else if (blk == 130) {
    for (int i = tid; i < 4096; i += 256) out[O3 + i] = c_cur[i];
  } else {
    if (tid < 128) rowsum[tid] = 0.f;
  }
}

// scale by pg/rowsum + OOV cols
__global__ __launch_bounds__(256) void k_scale(
    float* __restrict__ out, const float* __restrict__ pgen,
    const float* __restrict__ rowsum, const float* __restrict__ ez)
{
  int orow = blockIdx.x, cy = blockIdx.y, tid = threadIdx.x;
  int b = orow >> 4, t = orow & 15;
  float sc = pgen[t*8+b] / rowsum[orow];
  int c0 = cy*6256;
  int c1 = (cy == 7) ? VE : c0 + 6256;
  float* row = out + (size_t)orow*VE;
  for (int c = c0 + tid*4; c < c1; c += 1024) {
    if (c + 4 <= VV && c + 4 <= c1) {
      float4 v = *(float4*)(row + c);
      v.x *= sc; v.y *= sc; v.z *= sc; v.w *= sc;
      *(float4*)(row + c) = v;
    } else {
      for (int e = 0; e < 4; ++e) {
        int cc2 = c + e;
        if (cc2 < c1) row[cc2] = (cc2 < VV) ? row[cc2]*sc : ez[b*OOVn + cc2 - VV];
      }
    }
  }
}

// copy-mechanism scatter
__global__ __launch_bounds__(256) void k_scatter(
    float* __restrict__ out, const float* __restrict__ pgen,
    const int* __restrict__ extidx)
{
  int m = blockIdx.x, tid = threadIdx.x;  // m = t*8+b
  int b = m & 7, t = m >> 3;
  float* row = out + ((size_t)(b*TT + t))*VE;
  float onem = 1.0f - pgen[m];
  const float* pr = out + O4 + ((size_t)(b*TT+t))*SS;
  for (int s = tid; s < SS; s += 256) {
    int ix = extidx[b*SS + s];
    atomicAdd(&row[ix], onem * pr[s]);
  }
}

extern "C" void kernel_launch(void* const* d_in, const int* in_sizes, int n_in,
                              void* d_out, int out_size, void* d_ws, size_t ws_size,
                              hipStream_t stream)
{
  (void)in_sizes; (void)n_in; (void)out_size; (void)ws_size;
  const float* emb      = (const float*)d_in[0];
  const float* context  = (const float*)d_in[1];
  const float* h0       = (const float*)d_in[2];
  const float* c0       = (const float*)d_in[3];
  const float* enc      = (const float*)d_in[4];
  const float* masks    = (const float*)d_in[5];
  const float* ez       = (const float*)d_in[6];
  const int*   extidx   = (const int*)d_in[7];
  const float* coverage = (const float*)d_in[8];
  const float* wih      = (const float*)d_in[9];
  const float* whh      = (const float*)d_in[10];
  const float* bih      = (const float*)d_in[11];
  const float* bhh      = (const float*)d_in[12];
  const float* covw     = (const float*)d_in[13];
  const float* ew       = (const float*)d_in[14];
  const float* eb       = (const float*)d_in[15];
  const float* vvec     = (const float*)d_in[16];
  const float* xw       = (const float*)d_in[17];
  const float* xb       = (const float*)d_in[18];
  const float* aw       = (const float*)d_in[19];
  const float* ab       = (const float*)d_in[20];
  const float* vw       = (const float*)d_in[21];
  const float* vb       = (const float*)d_in[22];
  const float* pw       = (const float*)d_in[23];
  const float* pb       = (const float*)d_in[24];
  float* out = (float*)d_out;

  float* ws = (float*)d_ws;
  float* A1       = ws;                 // 128 x 1024 [h | ctx]
  float* c_cur    = ws + 131072;        // 4096
  unsigned short* attnd_bf = (unsigned short*)(ws + 139264);  // 128x512
  float* pgen     = ws + 172032;        // 128
  float* gb       = ws + 172160;        // 2048
  float* q        = ws + 174208;        // 640
  float* qb       = ws + 174848;        // 1
  float* d1       = ws + 174852;        // 128
  float* d2       = ws + 174980;        // 128
  float* rowsum   = ws + 175108;        // 128

  unsigned short* G     = (unsigned short*)(out + G_OFF);
  unsigned short* ewhb  = (unsigned short*)(out + EWHB_OFF);
  unsigned short* encG  = (unsigned short*)(out + ENCG_OFF);
  unsigned short* encpb = (unsigned short*)(out + ENCP_OFF);
  float*          PM    = out + PM_OFF;

  // Prologue
  p_wx<<<1280, 256, 0, stream>>>(wih, whh, xw, ew, G, ewhb);
  p_small<<<12, 256, 0, stream>>>(wih, bih, bhh, xb, xw, pw, pb, gb, q, qb, d1, d2);
  // encG[b] = Wx_ctx @ enc_b^T  (A = G cols 128..639, bf16; batched over b)
  gemm128<1,1,0,0><<<dim3(16,4,8), 256, 0, stream>>>(
      (const void*)(G + 128), 1152, enc, 512, (const float*)nullptr,
      (void*)encG, 400L, 400, 512, (long)400*512, (long)2048*400, nullptr);
  // encp = bf16(enc @ energy_w[:,512:].T)
  gemm128<0,1,0,0><<<dim3(25,4,1), 256, 0, stream>>>(
      (const void*)enc, 512, ew + 512, 1024, (const float*)nullptr,
      (void*)encpb, 512L, 512, 512, 0L, 0L, nullptr);

  for (int t = 0; t < TT; ++t) {
    s1g<<<256, 256, 0, stream>>>(G, encG, gb, emb, context, h0, c0, coverage,
                                 PM, d1, d2, A1, c_cur, out, t);
    s23<<<64, 256, 0, stream>>>(ewhb, eb, A1, encpb, vvec, covw, masks,
                                coverage, out + O6, PM, d1, d2, t);
  }

  ctx_all<<<32, 256, 0, stream>>>(PM, d1, d2, enc, A1, out);
  e_pgen<<<132, 256, 0, stream>>>(A1, c_cur, emb, context, pw, q, qb, pgen, rowsum, out);
  // attnd_bf = bf16([h|ctx] @ attnd_w.T + attnd_b)
  gemm128<0,1,0,0><<<dim3(1,4,1), 256, 0, stream>>>(
      (const void*)A1, 1024, aw, 1024, ab,
      (void*)attnd_bf, 512L, 512, 1024, 0L, 0L, nullptr);
  // logits: exp(attnd_bf @ vocab_w.T + vb) -> out rows (b*16+t), + rowsums
  gemm128<1,0,1,1><<<dim3(1,391,1), 256, 0, stream>>>(
      (const void*)attnd_bf, 512, vw, 512, vb,
      (void*)out, (long)VE, VV, 512, 0L, 0L, rowsum);
  k_scale<<<dim3(128,8), 256, 0, stream>>>(out, pgen, rowsum, ez);
  k_scatter<<<128, 256, 0, stream>>>(out, pgen, extidx);
}

// Round 7
// 961.632 us; speedup vs baseline: 1.2598x; 1.1357x over previous
//
#include <hip/hip_runtime.h>
#include <math.h>

#define BB 8
#define TT 16
#define SS 400
#define HH 512
#define EE 128
#define VV 50000
#define VE 50050
#define OOVn 50

// output offsets (floats)
#define O1 6406400
#define O2 6410496
#define O3 6414592
#define O4 6418688
#define O5 6469888
#define O6 6469896

// scratch inside out0 logits region (float offsets; dead until logits GEMM)
#define G_OFF    0          // 2048x1152 ushort = 1,179,648 f
#define EWHB_OFF 1179648    // 512x512  ushort =   131,072 f -> ends 1,310,720
#define ENCG_OFF 1310720    // 8x2048x400 ushort = 3,276,800 f -> ends 4,587,520
#define WXF_OFF  4600000    // 2048x512 fp32 = 1,048,576 f (dead after encG gemm)
#define ENCP_OFF 4600000    // 3200x512 ushort = 819,200 f (overwrites WXF - ok)
#define PM_OFF   5700000    // 16x8x400 fp32 = 51,200 f -> ends 5,751,200

typedef __attribute__((ext_vector_type(4))) float floatx4;
typedef __attribute__((ext_vector_type(8))) short short8;
typedef __attribute__((ext_vector_type(8))) unsigned short ushort8_t;
typedef __attribute__((ext_vector_type(4))) unsigned short ushort4_t;

__device__ __forceinline__ float sigm(float x){ return 1.0f/(1.0f+__expf(-x)); }
__device__ __forceinline__ float ftanh(float x){
  float e = __expf(2.0f*x); return 1.0f - 2.0f/(e + 1.0f);
}
__device__ __forceinline__ unsigned short f2bf(float f){
  union { float f; unsigned int u; } v; v.f = f;
  unsigned int u = v.u;
  return (unsigned short)((u + 0x7FFFu + ((u >> 16) & 1u)) >> 16);
}
__device__ __forceinline__ float bfu(unsigned short u){
  union { unsigned int i; float f; } v; v.i = ((unsigned int)u) << 16; return v.f;
}

// ---------------------------------------------------------------------------
// gemm_bt (R3-measured best for mid-size GEMMs): 128(M) x 64(N) tile,
// register-batched staging + LDS. fp32 in, bf16 MFMA, fp32/bf16 out.
// ---------------------------------------------------------------------------
__global__ __launch_bounds__(256)
void gemm_bt(const float* __restrict__ A, int lda,
             const float* __restrict__ Bm, int ldb,
             const float* __restrict__ bias,
             float* __restrict__ Cm, int ldc,
             int N, int K, int permute, int obf,
             long bsB, long bsC)
{
  __shared__ unsigned short Ash[128*72];
  __shared__ unsigned short Bsh[64*72];
  int tid = threadIdx.x;
  int mbase = blockIdx.x * 128;
  int nbase = blockIdx.y * 64;
  long z = blockIdx.z;
  const float* Bz = Bm + z*bsB;
  int wave = tid >> 6, lane = tid & 63;
  int wm = (wave & 1) * 64, wn = (wave >> 1) * 32;
  int fl = lane & 15, quad = lane >> 4;

  floatx4 acc[4][2];
  for (int i=0;i<4;i++) for(int j=0;j<2;j++) acc[i][j] = (floatx4)(0.0f);

  for (int kc = 0; kc < K; kc += 64) {
    float4 ra[8], rb[4];
#pragma unroll
    for (int i = 0; i < 8; ++i) {
      int idx = tid + i*256;
      int row = idx >> 4;
      int c4 = (idx & 15) << 2;
      ra[i] = *(const float4*)(A + (size_t)(mbase+row)*lda + kc + c4);
    }
#pragma unroll
    for (int i = 0; i < 4; ++i) {
      int idx = tid + i*256;
      int row = idx >> 4;
      int c4 = (idx & 15) << 2;
      int gn = nbase + row;
      if (gn < N) rb[i] = *(const float4*)(Bz + (size_t)gn*ldb + kc + c4);
      else { rb[i].x = 0.f; rb[i].y = 0.f; rb[i].z = 0.f; rb[i].w = 0.f; }
    }
    __syncthreads();
#pragma unroll
    for (int i = 0; i < 8; ++i) {
      int idx = tid + i*256;
      int o = (idx >> 4)*72 + ((idx & 15) << 2);
      Ash[o+0]=f2bf(ra[i].x); Ash[o+1]=f2bf(ra[i].y); Ash[o+2]=f2bf(ra[i].z); Ash[o+3]=f2bf(ra[i].w);
    }
#pragma unroll
    for (int i = 0; i < 4; ++i) {
      int idx = tid + i*256;
      int o = (idx >> 4)*72 + ((idx & 15) << 2);
      Bsh[o+0]=f2bf(rb[i].x); Bsh[o+1]=f2bf(rb[i].y); Bsh[o+2]=f2bf(rb[i].z); Bsh[o+3]=f2bf(rb[i].w);
    }
    __syncthreads();
#pragma unroll
    for (int ks = 0; ks < 2; ++ks) {
      short8 af[4], bfr[2];
      int ko = ks*32 + quad*8;
#pragma unroll
      for (int i=0;i<4;i++) af[i]  = *(const short8*)&Ash[(wm + i*16 + fl)*72 + ko];
#pragma unroll
      for (int j=0;j<2;j++) bfr[j] = *(const short8*)&Bsh[(wn + j*16 + fl)*72 + ko];
#pragma unroll
      for (int i=0;i<4;i++)
#pragma unroll
        for (int j=0;j<2;j++)
          acc[i][j] = __builtin_amdgcn_mfma_f32_16x16x32_bf16(af[i], bfr[j], acc[i][j], 0,0,0);
    }
    __syncthreads();
  }
  for (int i=0;i<4;i++){
    for (int j=0;j<2;j++){
      int nc = nbase + wn + j*16 + fl;
      if (nc >= N) continue;
      float bv = bias ? bias[nc] : 0.0f;
      for (int r=0;r<4;r++){
        int mg = mbase + wm + i*16 + quad*4 + r;
        int orow = permute ? ((mg & 7)*16 + (mg >> 3)) : mg;
        float v = acc[i][j][r] + bv;
        long ci = (long)orow*ldc + nc + z*bsC;
        if (obf) ((unsigned short*)Cm)[ci] = f2bf(v);
        else     Cm[ci] = v;
      }
    }
  }
}

// ---------------------------------------------------------------------------
// gemm128 (R6-measured best for the big HBM logits GEMM): 128x128 tile,
// register prefetch pipeline. Used ONLY for logits (ABF=1,EXPO=1,PERM=1).
// ---------------------------------------------------------------------------
template<int ABF, int OBF, int EXPO, int PERM>
__global__ __launch_bounds__(256) void gemm128(
    const void* __restrict__ Ap, int lda,
    const float* __restrict__ Bm, int ldb,
    const float* __restrict__ bias,
    void* __restrict__ Cp, long ldc,
    int N, int K, long bsB, long bsC,
    float* __restrict__ rowsum)
{
  __shared__ unsigned short Ash[128*72];
  __shared__ unsigned short Bsh[128*72];
  __shared__ float rowpart[128];
  int tid = threadIdx.x;
  int mbase = blockIdx.x * 128;
  int nbase = blockIdx.y * 128;
  const float* Bz = Bm + (long)blockIdx.z * bsB;
  int wave = tid >> 6, lane = tid & 63;
  int wm = (wave & 1)*64, wn = (wave >> 1)*64;
  int fl = lane & 15, quad = lane >> 4;

  floatx4 acc[4][4];
#pragma unroll
  for (int i=0;i<4;i++)
#pragma unroll
    for(int j=0;j<4;j++) acc[i][j] = (floatx4)(0.0f);
  if (EXPO && tid < 128) rowpart[tid] = 0.f;

  ushort8_t rau[4];
  float4 raf[8];
  float4 rbf[8];

  if (ABF) {
    const unsigned short* Au = (const unsigned short*)Ap;
#pragma unroll
    for (int i=0;i<4;i++){
      int idx = tid + i*256;
      int row = idx >> 3, c8 = (idx & 7) << 3;
      rau[i] = *(const ushort8_t*)(Au + (size_t)(mbase+row)*lda + c8);
    }
  } else {
    const float* Af = (const float*)Ap;
#pragma unroll
    for (int i=0;i<8;i++){
      int idx = tid + i*256;
      int row = idx >> 4, c4 = (idx & 15) << 2;
      raf[i] = *(const float4*)(Af + (size_t)(mbase+row)*lda + c4);
    }
  }
#pragma unroll
  for (int i=0;i<8;i++){
    int idx = tid + i*256;
    int row = idx >> 4, c4 = (idx & 15) << 2;
    int gn = nbase + row;
    if (gn < N) rbf[i] = *(const float4*)(Bz + (size_t)gn*ldb + c4);
    else { rbf[i].x=0.f; rbf[i].y=0.f; rbf[i].z=0.f; rbf[i].w=0.f; }
  }

  for (int kc = 0; kc < K; kc += 64) {
    __syncthreads();
    if (ABF) {
#pragma unroll
      for (int i=0;i<4;i++){
        int idx = tid + i*256;
        int o = (idx >> 3)*72 + ((idx & 7) << 3);
        *(ushort8_t*)&Ash[o] = rau[i];
      }
    } else {
#pragma unroll
      for (int i=0;i<8;i++){
        int idx = tid + i*256;
        int o = (idx >> 4)*72 + ((idx & 15) << 2);
        Ash[o+0]=f2bf(raf[i].x); Ash[o+1]=f2bf(raf[i].y); Ash[o+2]=f2bf(raf[i].z); Ash[o+3]=f2bf(raf[i].w);
      }
    }
#pragma unroll
    for (int i=0;i<8;i++){
      int idx = tid + i*256;
      int o = (idx >> 4)*72 + ((idx & 15) << 2);
      Bsh[o+0]=f2bf(rbf[i].x); Bsh[o+1]=f2bf(rbf[i].y); Bsh[o+2]=f2bf(rbf[i].z); Bsh[o+3]=f2bf(rbf[i].w);
    }
    __syncthreads();
    int kn = kc + 64;
    if (kn < K) {
      if (ABF) {
        const unsigned short* Au = (const unsigned short*)Ap;
#pragma unroll
        for (int i=0;i<4;i++){
          int idx = tid + i*256;
          int row = idx >> 3, c8 = (idx & 7) << 3;
          rau[i] = *(const ushort8_t*)(Au + (size_t)(mbase+row)*lda + kn + c8);
        }
      } else {
        const float* Af = (const float*)Ap;
#pragma unroll
        for (int i=0;i<8;i++){
          int idx = tid + i*256;
          int row = idx >> 4, c4 = (idx & 15) << 2;
          raf[i] = *(const float4*)(Af + (size_t)(mbase+row)*lda + kn + c4);
        }
      }
#pragma unroll
      for (int i=0;i<8;i++){
        int idx = tid + i*256;
        int row = idx >> 4, c4 = (idx & 15) << 2;
        int gn = nbase + row;
        if (gn < N) rbf[i] = *(const float4*)(Bz + (size_t)gn*ldb + kn + c4);
        else { rbf[i].x=0.f; rbf[i].y=0.f; rbf[i].z=0.f; rbf[i].w=0.f; }
      }
    }
#pragma unroll
    for (int ks=0; ks<2; ++ks){
      short8 af[4], bfr[4];
      int ko = ks*32 + quad*8;
#pragma unroll
      for (int i=0;i<4;i++) af[i]  = *(const short8*)&Ash[(wm + i*16 + fl)*72 + ko];
#pragma unroll
      for (int j=0;j<4;j++) bfr[j] = *(const short8*)&Bsh[(wn + j*16 + fl)*72 + ko];
#pragma unroll
      for (int i=0;i<4;i++)
#pragma unroll
        for (int j=0;j<4;j++)
          acc[i][j] = __builtin_amdgcn_mfma_f32_16x16x32_bf16(af[i], bfr[j], acc[i][j], 0,0,0);
    }
  }

  if (EXPO) __syncthreads();
#pragma unroll
  for (int i=0;i<4;i++){
#pragma unroll
    for (int r=0;r<4;r++){
      int mg = mbase + wm + i*16 + quad*4 + r;
      int orow = PERM ? ((mg & 7)*16 + (mg >> 3)) : mg;
      float rs = 0.f;
#pragma unroll
      for (int j=0;j<4;j++){
        int nc = nbase + wn + j*16 + fl;
        if (nc >= N) continue;
        float v = acc[i][j][r] + (bias ? bias[nc] : 0.f);
        long ci = (long)orow*ldc + nc + (long)blockIdx.z*bsC;
        if (EXPO) {
          float e = __expf(v);
          ((float*)Cp)[ci] = e;
          rs += e;
        } else if (OBF) {
          ((unsigned short*)Cp)[ci] = f2bf(v);
        } else {
          ((float*)Cp)[ci] = v;
        }
      }
      if (EXPO) atomicAdd(&rowpart[mg & 127], rs);
    }
  }
  if (EXPO) {
    __syncthreads();
    if (tid < 128) {
      int orow = (tid & 7)*16 + (tid >> 3);
      atomicAdd(&rowsum[orow], rowpart[tid]);
    }
  }
}

// ---------------------------------------------------------------------------
// Prologue P1: G = [Wx (640) | W_hh (512)] bf16; wxf = Wx_ctx fp32; ewhb.
// ---------------------------------------------------------------------------
__global__ __launch_bounds__(256) void p_wx(const float* __restrict__ wih,
    const float* __restrict__ whh, const float* __restrict__ xcw,
    const float* __restrict__ ew,
    unsigned short* __restrict__ G, float* __restrict__ wxf,
    unsigned short* __restrict__ ewhb)
{
  int blk = blockIdx.x, tid = threadIdx.x;
  if (blk < 640) {
    int rt = blk / 10, ct = blk % 10;
    __shared__ float wl[32*128];
    __shared__ float xl[128*64];
    for (int i = tid; i < 4096; i += 256) {
      int r = i >> 7, k = i & 127;
      wl[i] = wih[(size_t)(rt*32+r)*128 + k];
    }
    for (int i = tid; i < 8192; i += 256) {
      int e = i >> 6, c = i & 63;
      xl[i] = xcw[(size_t)e*640 + ct*64 + c];
    }
    __syncthreads();
    for (int o = tid; o < 2048; o += 256) {
      int r = o >> 6, c = o & 63;
      float acc = 0.f;
      for (int e = 0; e < 128; ++e) acc += wl[r*128+e]*xl[e*64+c];
      G[(size_t)(rt*32+r)*1152 + ct*64 + c] = f2bf(acc);
      int col = ct*64 + c;
      if (col >= 128) wxf[(size_t)(rt*32+r)*512 + col - 128] = acc;
    }
  } else if (blk < 1152) {
    int idx = blk - 640;  // 0..511
    for (int q = 0; q < 2; ++q) {
      int n = idx*2048 + q*1024 + tid*4;
      int r = n >> 9, k = n & 511;
      float4 v = *(const float4*)(whh + n);
      ushort4_t s; s[0]=f2bf(v.x); s[1]=f2bf(v.y); s[2]=f2bf(v.z); s[3]=f2bf(v.w);
      *(ushort4_t*)(G + (size_t)r*1152 + 640 + k) = s;
    }
  } else {
    int idx = blk - 1152;  // 0..127
    for (int q = 0; q < 2; ++q) {
      size_t n = (size_t)idx*2048 + q*1024 + tid*4;
      int p = (int)(n >> 9), k = (int)(n & 511);
      float4 v = *(const float4*)(ew + (size_t)p*1024 + k);
      ushort4_t s; s[0]=f2bf(v.x); s[1]=f2bf(v.y); s[2]=f2bf(v.z); s[3]=f2bf(v.w);
      *(ushort4_t*)(ewhb + n) = s;
    }
  }
}

// Prologue P2: gb = b_ih+b_hh+W_ih@xb ; q = xctx_w^T@pw_x ; qb ; zero d1/d2
__global__ __launch_bounds__(256) void p_small(const float* __restrict__ wih,
    const float* __restrict__ bih, const float* __restrict__ bhh,
    const float* __restrict__ xb, const float* __restrict__ xcw,
    const float* __restrict__ pw, const float* __restrict__ pb,
    float* __restrict__ gb, float* __restrict__ q, float* __restrict__ qb,
    float* __restrict__ d1, float* __restrict__ d2)
{
  int blk = blockIdx.x, tid = threadIdx.x;
  if (blk < 8) {
    __shared__ float xbl[128];
    if (tid < 128) xbl[tid] = xb[tid];
    __syncthreads();
    int r = blk*256 + tid;
    const float* wr = wih + (size_t)r*128;
    float acc = bih[r] + bhh[r];
    for (int e = 0; e < 128; ++e) acc += wr[e]*xbl[e];
    gb[r] = acc;
  } else if (blk < 11) {
    int o = (blk-8)*256 + tid;
    if (o < 640) {
      float acc = 0.f;
      for (int e = 0; e < 128; ++e) acc += pw[1024+e]*xcw[(size_t)e*640 + o];
      q[o] = acc;
    }
  } else {
    if (tid == 0) {
      float acc = 0.f;
      for (int e = 0; e < 128; ++e) acc += pw[1024+e]*xb[e];
      qb[0] = acc + pb[0];
    }
    if (tid < 128) { d1[tid] = 0.f; d2[tid] = 0.f; }
  }
}

// ---------------------------------------------------------------------------
// S1 (512 thr, 8-way K-split for latency hiding): gates -> LSTM -> h,c.
// ---------------------------------------------------------------------------
__global__ __launch_bounds__(512) void s1g(
    const unsigned short* __restrict__ G, const unsigned short* __restrict__ encG,
    const float* __restrict__ gb,
    const float* __restrict__ emb, const float* __restrict__ context,
    const float* __restrict__ h0, const float* __restrict__ c0,
    const float* __restrict__ coverage,
    const float* __restrict__ PM, const float* __restrict__ d1,
    const float* __restrict__ d2,
    float* __restrict__ A1, float* __restrict__ c_cur,
    float* __restrict__ out, int t)
{
  __shared__ float ueh[8][652];   // [emb(128) | h(512)]
  __shared__ float uc[8][524];    // t==0: context(512) ; t>=1: probs(400)
  __shared__ float part[512];
  __shared__ float gl[64];
  __shared__ float invs[8];
  int tid = threadIdx.x, blk = blockIdx.x;

  if (t >= 1 && tid < 8)
    invs[tid] = 1.0f / (d2[(t-1)*8 + tid] + 1e-12f*d1[(t-1)*8 + tid]);
  __syncthreads();

  for (int i = 0; i < 3; ++i) {
    int slot = i*512 + tid;
    if (slot < 1280) {
      int b = slot / 160, sl = slot - b*160;
      if (sl < 32) {
        *(float4*)&ueh[b][sl*4] = *(const float4*)(emb + (size_t)(b*16+t)*128 + sl*4);
      } else {
        int qq = sl - 32;
        const float* hsrc = t ? (A1 + ((size_t)((t-1)*8+b))*1024) : (h0 + b*512);
        *(float4*)&ueh[b][128 + qq*4] = *(const float4*)(hsrc + qq*4);
      }
    }
  }
  if (t == 0) {
    for (int i = 0; i < 2; ++i) {
      int slot = i*512 + tid;
      int b = slot >> 7, sl = slot & 127;
      *(float4*)&uc[b][sl*4] = *(const float4*)(context + b*512 + sl*4);
    }
  } else {
    const float* pmsrc = PM + (size_t)(t-1)*3200;
    for (int i = 0; i < 2; ++i) {
      int slot = i*512 + tid;
      if (slot < 800) {
        int b = slot / 100, sl = slot - b*100;
        float4 p4 = *(const float4*)(pmsrc + b*400 + sl*4);
        float iv = invs[b];
        p4.x *= iv; p4.y *= iv; p4.z *= iv; p4.w *= iv;
        *(float4*)&uc[b][sl*4] = p4;
      }
    }
  }
  __syncthreads();

  if (t >= 1 && blk < 8) {
    int b = blk;
    const float* covprev = (t == 1) ? (coverage + b*400)
                                    : (out + O6 + ((size_t)(b*16 + t-2))*400);
    size_t o = ((size_t)(b*16 + t-1))*400;
    for (int s = tid; s < 400; s += 512) {
      float pr = uc[b][s];
      out[O4 + o + s] = pr;
      out[O6 + o + s] = covprev[s] + pr;
    }
  }

  int dot = tid >> 3, kq = tid & 7;   // 64 dots (8 rr x 8 b), 8-way k-split
  int rr = dot >> 3, b = dot & 7;
  int gate = rr >> 1, jj = rr & 1;
  int r = gate*512 + blk*2 + jj;
  const unsigned short* gr = G + (size_t)r*1152;
  float acc = 0.f;
  // emb (128): 2 chunks of 8, stride 64
  {
    const unsigned short* gp = gr + kq*8;
    const float* up = &ueh[b][kq*8];
#pragma unroll
    for (int i = 0; i < 2; ++i) {
      ushort8_t w8 = *(const ushort8_t*)(gp + i*64);
      float4 u0 = *(const float4*)(up + i*64);
      float4 u1 = *(const float4*)(up + i*64 + 4);
      acc += bfu(w8[0])*u0.x + bfu(w8[1])*u0.y + bfu(w8[2])*u0.z + bfu(w8[3])*u0.w
           + bfu(w8[4])*u1.x + bfu(w8[5])*u1.y + bfu(w8[6])*u1.z + bfu(w8[7])*u1.w;
    }
  }
  // h (512): 8 chunks of 8, stride 64
  {
    const unsigned short* gp = gr + 640 + kq*8;
    const float* up = &ueh[b][128 + kq*8];
#pragma unroll
    for (int i = 0; i < 8; ++i) {
      ushort8_t w8 = *(const ushort8_t*)(gp + i*64);
      float4 u0 = *(const float4*)(up + i*64);
      float4 u1 = *(const float4*)(up + i*64 + 4);
      acc += bfu(w8[0])*u0.x + bfu(w8[1])*u0.y + bfu(w8[2])*u0.z + bfu(w8[3])*u0.w
           + bfu(w8[4])*u1.x + bfu(w8[5])*u1.y + bfu(w8[6])*u1.z + bfu(w8[7])*u1.w;
    }
  }
  if (t == 0) {
    const unsigned short* gp = gr + 128 + kq*8;
    const float* up = &uc[b][kq*8];
#pragma unroll
    for (int i = 0; i < 8; ++i) {
      ushort8_t w8 = *(const ushort8_t*)(gp + i*64);
      float4 u0 = *(const float4*)(up + i*64);
      float4 u1 = *(const float4*)(up + i*64 + 4);
      acc += bfu(w8[0])*u0.x + bfu(w8[1])*u0.y + bfu(w8[2])*u0.z + bfu(w8[3])*u0.w
           + bfu(w8[4])*u1.x + bfu(w8[5])*u1.y + bfu(w8[6])*u1.z + bfu(w8[7])*u1.w;
    }
  } else {
    const unsigned short* gp = encG + ((size_t)(b*2048 + r))*400 + kq*8;
    const float* up = &uc[b][kq*8];
#pragma unroll
    for (int i = 0; i < 6; ++i) {     // 6*64 = 384
      ushort8_t w8 = *(const ushort8_t*)(gp + i*64);
      float4 u0 = *(const float4*)(up + i*64);
      float4 u1 = *(const float4*)(up + i*64 + 4);
      acc += bfu(w8[0])*u0.x + bfu(w8[1])*u0.y + bfu(w8[2])*u0.z + bfu(w8[3])*u0.w
           + bfu(w8[4])*u1.x + bfu(w8[5])*u1.y + bfu(w8[6])*u1.z + bfu(w8[7])*u1.w;
    }
    if (kq < 2) {                     // remainder 384..399
      ushort8_t w8 = *(const ushort8_t*)(gp + 6*64);
      float4 u0 = *(const float4*)(up + 6*64);
      float4 u1 = *(const float4*)(up + 6*64 + 4);
      acc += bfu(w8[0])*u0.x + bfu(w8[1])*u0.y + bfu(w8[2])*u0.z + bfu(w8[3])*u0.w
           + bfu(w8[4])*u1.x + bfu(w8[5])*u1.y + bfu(w8[6])*u1.z + bfu(w8[7])*u1.w;
    }
  }
  part[tid] = acc;
  __syncthreads();
  if (tid < 64) {
    int rr2 = tid >> 3;
    int r2 = (rr2 >> 1)*512 + blk*2 + (rr2 & 1);
    float s2 = gb[r2];
#pragma unroll
    for (int q2 = 0; q2 < 8; ++q2) s2 += part[tid*8 + q2];
    gl[tid] = s2;
  }
  __syncthreads();
  if (tid < 16) {
    int jj2 = tid >> 3, b2 = tid & 7;
    float gi = gl[(0*2+jj2)*8 + b2];
    float gf = gl[(1*2+jj2)*8 + b2];
    float gg = gl[(2*2+jj2)*8 + b2];
    float go = gl[(3*2+jj2)*8 + b2];
    int j = blk*2 + jj2;
    float cp = t ? c_cur[b2*512+j] : c0[b2*512+j];
    float cn = sigm(gf)*cp + sigm(gi)*ftanh(gg);
    float hn = sigm(go)*ftanh(cn);
    c_cur[b2*512+j] = cn;
    A1[((size_t)(t*8+b2))*1024 + j] = hn;
  }
}

// ---------------------------------------------------------------------------
// S23: fused hp + energy + exp. 128 blocks (8 b x 16 s-chunks of 25).
// ---------------------------------------------------------------------------
__global__ __launch_bounds__(256) void s23(
    const unsigned short* __restrict__ ewhb, const float* __restrict__ eb,
    const float* __restrict__ A1, const unsigned short* __restrict__ encpb,
    const float* __restrict__ vvec, const float* __restrict__ covw,
    const float* __restrict__ masks, const float* __restrict__ coverage,
    const float* __restrict__ out6v, float* __restrict__ PM,
    float* __restrict__ d1, float* __restrict__ d2, int t)
{
  int tid = threadIdx.x;
  int b = blockIdx.x >> 4, sc = blockIdx.x & 15;
  __shared__ float hl[512];
  __shared__ float hps[512];
  __shared__ float red1[4], red2[4];
  for (int k = tid; k < 512; k += 256) hl[k] = A1[((size_t)(t*8+b))*1024 + k];
  __syncthreads();
#pragma unroll
  for (int pi = 0; pi < 2; ++pi) {
    int p = tid + pi*256;
    const unsigned short* wp = ewhb + (size_t)p*512;
    float acc = 0.f;
#pragma unroll 4
    for (int k = 0; k < 512; k += 8) {
      ushort8_t w8 = *(const ushort8_t*)(wp + k);
      float4 u0 = *(const float4*)(hl + k);
      float4 u1 = *(const float4*)(hl + k + 4);
      acc += bfu(w8[0])*u0.x + bfu(w8[1])*u0.y + bfu(w8[2])*u0.z + bfu(w8[3])*u0.w
           + bfu(w8[4])*u1.x + bfu(w8[5])*u1.y + bfu(w8[6])*u1.z + bfu(w8[7])*u1.w;
    }
    hps[p] = eb[p] + acc;
  }
  __syncthreads();
  int w = tid >> 6, lane = tid & 63;
  int h0i = lane*8;
  float hpv[8], vv[8], cw[8];
  {
    float4 a0 = *(const float4*)&hps[h0i], a1 = *(const float4*)&hps[h0i+4];
    hpv[0]=a0.x; hpv[1]=a0.y; hpv[2]=a0.z; hpv[3]=a0.w;
    hpv[4]=a1.x; hpv[5]=a1.y; hpv[6]=a1.z; hpv[7]=a1.w;
    float4 v0 = *(const float4*)(vvec+h0i), v1 = *(const float4*)(vvec+h0i+4);
    vv[0]=v0.x; vv[1]=v0.y; vv[2]=v0.z; vv[3]=v0.w;
    vv[4]=v1.x; vv[5]=v1.y; vv[6]=v1.z; vv[7]=v1.w;
    float4 c0v = *(const float4*)(covw+h0i), c1v = *(const float4*)(covw+h0i+4);
    cw[0]=c0v.x; cw[1]=c0v.y; cw[2]=c0v.z; cw[3]=c0v.w;
    cw[4]=c1v.x; cw[5]=c1v.y; cw[6]=c1v.z; cw[7]=c1v.w;
  }
  const float* covp = t ? (out6v + ((size_t)(b*16 + t-1))*400) : (coverage + b*400);
  float a1s = 0.f, a2s = 0.f;
  for (int sl = w; sl < 25; sl += 4) {
    int s = sc*25 + sl;
    float cv = covp[s];
    const unsigned short* ep = encpb + ((size_t)(b*400+s))*512 + h0i;
    ushort8_t e8 = *(const ushort8_t*)ep;
    float acc = 0.f;
#pragma unroll
    for (int i = 0; i < 8; ++i)
      acc += ftanh(hpv[i] + bfu(e8[i]) + cv*cw[i]) * vv[i];
    for (int off = 32; off > 0; off >>= 1) acc += __shfl_down(acc, off);
    if (lane == 0) {
      float pe = __expf(acc);
      float pmv = pe * masks[b*400 + s];
      PM[(size_t)t*3200 + b*400 + s] = pmv;
      a1s += pe; a2s += pmv;
    }
  }
  if (lane == 0) { red1[w] = a1s; red2[w] = a2s; }
  __syncthreads();
  if (tid == 0) {
    atomicAdd(&d1[t*8+b], red1[0]+red1[1]+red1[2]+red1[3]);
    atomicAdd(&d2[t*8+b], red2[0]+red2[1]+red2[2]+red2[3]);
  }
}

// ctx for ALL t (post-loop): A1 ctx cols; also out4/out6 for t=15.
__global__ __launch_bounds__(256) void ctx_all(
    const float* __restrict__ PM, const float* __restrict__ d1,
    const float* __restrict__ d2, const float* __restrict__ enc,
    float* __restrict__ A1, float* __restrict__ out)
{
  int tid = threadIdx.x;
  int b = blockIdx.x >> 2, cc = blockIdx.x & 3;
  __shared__ float prl[16][400];
  __shared__ float redbuf[16][128];
  __shared__ float invs[16];
  if (tid < 16) invs[tid] = 1.0f / (d2[tid*8+b] + 1e-12f*d1[tid*8+b]);
  __syncthreads();
  for (int i = 0; i < 7; ++i) {
    int slot = i*256 + tid;
    if (slot < 1600) {
      int tt = slot / 100, sl = slot - tt*100;
      float4 p4 = *(const float4*)(PM + (size_t)tt*3200 + b*400 + sl*4);
      float iv = invs[tt];
      p4.x *= iv; p4.y *= iv; p4.z *= iv; p4.w *= iv;
      *(float4*)&prl[tt][sl*4] = p4;
    }
  }
  __syncthreads();
  if (cc == 0) {
    size_t o15 = ((size_t)(b*16 + 15))*400;
    size_t o14 = ((size_t)(b*16 + 14))*400;
    for (int s = tid; s < 400; s += 256) {
      float pr = prl[15][s];
      out[O4 + o15 + s] = pr;
      out[O6 + o15 + s] = out[O6 + o14 + s] + pr;
    }
  }
  int c = cc*128 + (tid & 127);
  int sg = tid >> 7;
  float acc[16];
#pragma unroll
  for (int tt = 0; tt < 16; ++tt) acc[tt] = 0.f;
  for (int s = sg*200; s < sg*200 + 200; ++s) {
    float ev = enc[((size_t)(b*400 + s))*512 + c];
#pragma unroll
    for (int tt = 0; tt < 16; ++tt) acc[tt] += prl[tt][s]*ev;
  }
  if (sg == 1) {
#pragma unroll
    for (int tt = 0; tt < 16; ++tt) redbuf[tt][tid & 127] = acc[tt];
  }
  __syncthreads();
  if (sg == 0) {
#pragma unroll
    for (int tt = 0; tt < 16; ++tt)
      A1[((size_t)(tt*8+b))*1024 + 512 + c] = acc[tt] + redbuf[tt][tid & 127];
  }
}

// Epilogue: pgen all (t,b) + out1/2/3/5 + rowsum zero
__global__ __launch_bounds__(256) void e_pgen(
    const float* __restrict__ A1, const float* __restrict__ c_cur,
    const float* __restrict__ emb, const float* __restrict__ context,
    const float* __restrict__ pw, const float* __restrict__ q,
    const float* __restrict__ qb, float* __restrict__ pgen,
    float* __restrict__ rowsum, float* __restrict__ out)
{
  int blk = blockIdx.x, tid = threadIdx.x;
  if (blk < 128) {
    int m = blk, t = m >> 3, b = m & 7;
    const float* ctxT = A1 + (size_t)m*1024 + 512;
    const float* hT   = A1 + (size_t)m*1024;
    const float* embp = emb + (size_t)(b*16+t)*128;
    const float* ctxP = t ? (A1 + ((size_t)((t-1)*8+b))*1024 + 512) : (context + b*512);
    float acc = 0.f;
    for (int k = tid; k < 512; k += 256)
      acc += pw[k]*ctxT[k] + pw[512+k]*hT[k] + q[128+k]*ctxP[k];
    if (tid < 128) acc += q[tid]*embp[tid];
    for (int off = 32; off > 0; off >>= 1) acc += __shfl_down(acc, off);
    __shared__ float red[4];
    if (!(tid & 63)) red[tid>>6] = acc;
    __syncthreads();
    if (tid == 0) {
      float pg = sigm(red[0]+red[1]+red[2]+red[3] + qb[0]);
      pgen[m] = pg;
      if (t == 15) out[O5 + b] = pg;
    }
  } else if (blk == 128) {
    for (int i = tid; i < 4096; i += 256) {
      int b = i >> 9, j = i & 511;
      out[O1 + i] = A1[((size_t)(120+b))*1024 + 512 + j];
    }
  } else if (blk == 129) {
    for (int i = tid; i < 4096; i += 256) {
      int b = i >> 9, j = i & 511;
      out[O2 + i] = A1[((size_t)(120+b))*1024 + j];
    }
  } else if (blk == 130) {
    for (int i = tid; i < 4096; i += 256) out[O3 + i] = c_cur[i];
  } else {
    if (tid < 128) rowsum[tid] = 0.f;
  }
}

// scale by pg/rowsum + OOV cols
__global__ __launch_bounds__(256) void k_scale(
    float* __restrict__ out, const float* __restrict__ pgen,
    const float* __restrict__ rowsum, const float* __restrict__ ez)
{
  int orow = blockIdx.x, cy = blockIdx.y, tid = threadIdx.x;
  int b = orow >> 4, t = orow & 15;
  float sc = pgen[t*8+b] / rowsum[orow];
  int c0 = cy*6256;
  int c1 = (cy == 7) ? VE : c0 + 6256;
  float* row = out + (size_t)orow*VE;
  for (int c = c0 + tid*4; c < c1; c += 1024) {
    if (c + 4 <= VV && c + 4 <= c1) {
      float4 v = *(float4*)(row + c);
      v.x *= sc; v.y *= sc; v.z *= sc; v.w *= sc;
      *(float4*)(row + c) = v;
    } else {
      for (int e = 0; e < 4; ++e) {
        int cc2 = c + e;
        if (cc2 < c1) row[cc2] = (cc2 < VV) ? row[cc2]*sc : ez[b*OOVn + cc2 - VV];
      }
    }
  }
}

// copy-mechanism scatter
__global__ __launch_bounds__(256) void k_scatter(
    float* __restrict__ out, const float* __restrict__ pgen,
    const int* __restrict__ extidx)
{
  int m = blockIdx.x, tid = threadIdx.x;  // m = t*8+b
  int b = m & 7, t = m >> 3;
  float* row = out + ((size_t)(b*TT + t))*VE;
  float onem = 1.0f - pgen[m];
  const float* pr = out + O4 + ((size_t)(b*TT+t))*SS;
  for (int s = tid; s < SS; s += 256) {
    int ix = extidx[b*SS + s];
    atomicAdd(&row[ix], onem * pr[s]);
  }
}

extern "C" void kernel_launch(void* const* d_in, const int* in_sizes, int n_in,
                              void* d_out, int out_size, void* d_ws, size_t ws_size,
                              hipStream_t stream)
{
  (void)in_sizes; (void)n_in; (void)out_size; (void)ws_size;
  const float* emb      = (const float*)d_in[0];
  const float* context  = (const float*)d_in[1];
  const float* h0       = (const float*)d_in[2];
  const float* c0       = (const float*)d_in[3];
  const float* enc      = (const float*)d_in[4];
  const float* masks    = (const float*)d_in[5];
  const float* ez       = (const float*)d_in[6];
  const int*   extidx   = (const int*)d_in[7];
  const float* coverage = (const float*)d_in[8];
  const float* wih      = (const float*)d_in[9];
  const float* whh      = (const float*)d_in[10];
  const float* bih      = (const float*)d_in[11];
  const float* bhh      = (const float*)d_in[12];
  const float* covw     = (const float*)d_in[13];
  const float* ew       = (const float*)d_in[14];
  const float* eb       = (const float*)d_in[15];
  const float* vvec     = (const float*)d_in[16];
  const float* xw       = (const float*)d_in[17];
  const float* xb       = (const float*)d_in[18];
  const float* aw       = (const float*)d_in[19];
  const float* ab       = (const float*)d_in[20];
  const float* vw       = (const float*)d_in[21];
  const float* vb       = (const float*)d_in[22];
  const float* pw       = (const float*)d_in[23];
  const float* pb       = (const float*)d_in[24];
  float* out = (float*)d_out;

  float* ws = (float*)d_ws;
  float* A1       = ws;                 // 128 x 1024 [h | ctx]
  float* c_cur    = ws + 131072;        // 4096
  unsigned short* attnd_bf = (unsigned short*)(ws + 139264);  // 128x512
  float* pgen     = ws + 172032;        // 128
  float* gb       = ws + 172160;        // 2048
  float* q        = ws + 174208;        // 640
  float* qb       = ws + 174848;        // 1
  float* d1       = ws + 174852;        // 128
  float* d2       = ws + 174980;        // 128
  float* rowsum   = ws + 175108;        // 128

  unsigned short* G     = (unsigned short*)(out + G_OFF);
  unsigned short* ewhb  = (unsigned short*)(out + EWHB_OFF);
  unsigned short* encG  = (unsigned short*)(out + ENCG_OFF);
  float*          wxf   = out + WXF_OFF;
  unsigned short* encpb = (unsigned short*)(out + ENCP_OFF);
  float*          PM    = out + PM_OFF;

  // Prologue
  p_wx<<<1280, 256, 0, stream>>>(wih, whh, xw, ew, G, wxf, ewhb);
  p_small<<<12, 256, 0, stream>>>(wih, bih, bhh, xb, xw, pw, pb, gb, q, qb, d1, d2);
  // encG[b] = Wx_ctx @ enc_b^T  (bf16 out, batched over b)  [gemm_bt: R3-best]
  gemm_bt<<<dim3(16,7,8), 256, 0, stream>>>(wxf, 512, enc, 512,
      (const float*)nullptr, (float*)encG, 400, 400, 512, 0, 1,
      (long)400*512, (long)2048*400);
  // encp = bf16(enc @ energy_w[:,512:].T)  (overwrites wxf region - ok)
  gemm_bt<<<dim3(25,8,1), 256, 0, stream>>>(enc, 512, ew + 512, 1024,
      (const float*)nullptr, (float*)encpb, 512, 512, 512, 0, 1, 0, 0);

  for (int t = 0; t < TT; ++t) {
    s1g<<<256, 512, 0, stream>>>(G, encG, gb, emb, context, h0, c0, coverage,
                                 PM, d1, d2, A1, c_cur, out, t);
    s23<<<128, 256, 0, stream>>>(ewhb, eb, A1, encpb, vvec, covw, masks,
                                 coverage, out + O6, PM, d1, d2, t);
  }

  ctx_all<<<32, 256, 0, stream>>>(PM, d1, d2, enc, A1, out);
  e_pgen<<<132, 256, 0, stream>>>(A1, c_cur, emb, context, pw, q, qb, pgen, rowsum, out);
  // attnd_bf = bf16([h|ctx] @ attnd_w.T + attnd_b)  [gemm_bt]
  gemm_bt<<<dim3(1,8,1), 256, 0, stream>>>(A1, 1024, aw, 1024, ab,
      (float*)attnd_bf, 512, 512, 1024, 0, 1, 0, 0);
  // logits: exp(attnd_bf @ vocab_w.T + vb) -> out rows (b*16+t), + rowsums
  gemm128<1,0,1,1><<<dim3(1,391,1), 256, 0, stream>>>(
      (const void*)attnd_bf, 512, vw, 512, vb,
      (void*)out, (long)VE, VV, 512, 0L, 0L, rowsum);
  k_scale<<<dim3(128,8), 256, 0, stream>>>(out, pgen, rowsum, ez);
  k_scatter<<<128, 256, 0, stream>>>(out, pgen, extidx);
}